// Round 7
// baseline (205.073 us; speedup 1.0000x reference)
//
#include <hip/hip_runtime.h>
#include <hip/hip_bf16.h>

// Problem constants
#define NB 16        // batches
#define SS 2048      // S
#define FF 512       // F

typedef __bf16 bf16_t;
typedef __bf16 bf16x8 __attribute__((ext_vector_type(8)));
typedef __bf16 bf16x4 __attribute__((ext_vector_type(4)));
typedef float  f32x4  __attribute__((ext_vector_type(4)));

// ---------------------------------------------------------------- LN stats
__global__ __launch_bounds__(256) void stats_kernel(const float* __restrict__ x,
                                                    float* __restrict__ partials) {
    const int b = blockIdx.y;
    const float* xb = x + ((size_t)b << 20) + (size_t)blockIdx.x * 16384;
    float s = 0.0f, ss = 0.0f;
#pragma unroll
    for (int i = 0; i < 16; ++i) {
        const float4 v = *(const float4*)&xb[(threadIdx.x + i * 256) * 4];
        s  += v.x + v.y + v.z + v.w;
        ss += v.x * v.x + v.y * v.y + v.z * v.z + v.w * v.w;
    }
#pragma unroll
    for (int off = 32; off > 0; off >>= 1) {
        s  += __shfl_down(s, off);
        ss += __shfl_down(ss, off);
    }
    __shared__ float ps[4], pss[4];
    const int w = threadIdx.x >> 6, lane = threadIdx.x & 63;
    if (lane == 0) { ps[w] = s; pss[w] = ss; }
    __syncthreads();
    if (threadIdx.x == 0) {
        partials[b * 64 + blockIdx.x]        = ps[0] + ps[1] + ps[2] + ps[3];
        partials[1024 + b * 64 + blockIdx.x] = pss[0] + pss[1] + pss[2] + pss[3];
    }
}

__global__ __launch_bounds__(256) void finalize_stats(const float* __restrict__ partials,
                                                      float* __restrict__ musig) {
    const int tid = threadIdx.x;          // 0..255
    const int b = tid >> 4, i = tid & 15;
    float s = 0.f, ss = 0.f;
#pragma unroll
    for (int j = 0; j < 4; ++j) {
        s  += partials[b * 64 + i * 4 + j];
        ss += partials[1024 + b * 64 + i * 4 + j];
    }
#pragma unroll
    for (int off = 8; off > 0; off >>= 1) {
        s  += __shfl_xor(s, off);
        ss += __shfl_xor(ss, off);
    }
    if (i == 0) {
        const float inv_n = 1.0f / 1048576.0f;
        const float mu  = s * inv_n;
        const float var = ss * inv_n - mu * mu;
        musig[b]      = mu;
        musig[16 + b] = rsqrtf(var + 1e-5f);
    }
}

// ------------------------------------------------- x_norm -> Y bf16 [b][f][s]
__global__ __launch_bounds__(256) void ynorm_kernel(const float* __restrict__ x,
                                                    const float* __restrict__ lw,
                                                    const float* __restrict__ lb,
                                                    const float* __restrict__ musig,
                                                    bf16_t* __restrict__ Y) {
    __shared__ bf16_t t[32][33];
    const int b = blockIdx.z;
    const int f0 = blockIdx.x * 32, s0 = blockIdx.y * 32;
    const float mu = musig[b], rs = musig[16 + b];
    const int c = threadIdx.x & 31, rb = threadIdx.x >> 5;   // rb in 0..7
#pragma unroll
    for (int i = 0; i < 4; ++i) {
        const int s_loc = rb + i * 8;
        const size_t idx = (size_t)(s0 + s_loc) * FF + f0 + c;
        const float yv = (x[((size_t)b << 20) + idx] - mu) * rs * lw[idx] + lb[idx];
        t[s_loc][c] = (bf16_t)yv;
    }
    __syncthreads();
#pragma unroll
    for (int i = 0; i < 4; ++i) {
        const int f_loc = rb + i * 8;
        Y[((size_t)b << 20) + (size_t)(f0 + f_loc) * SS + s0 + c] = t[c][f_loc];
    }
}

// ---------------------------------------------------------------- Wv -> bf16
__global__ __launch_bounds__(256) void cast_wv(const float* __restrict__ Wv,
                                               bf16_t* __restrict__ Wvb) {
    const size_t i = ((size_t)blockIdx.x * 256 + threadIdx.x) * 4;
    const float4 v = *(const float4*)&Wv[i];
    bf16x4 o;
    o[0] = (bf16_t)v.x; o[1] = (bf16_t)v.y; o[2] = (bf16_t)v.z; o[3] = (bf16_t)v.w;
    *(bf16x4*)&Wvb[i] = o;
}

// -------------------------------------------------- Q,K: [b*F] rows, R=4 each
__global__ __launch_bounds__(256) void qk_kernel(const bf16_t* __restrict__ Y,
                                                 const float* __restrict__ Wq,
                                                 const float* __restrict__ bq,
                                                 const float* __restrict__ Wk,
                                                 const float* __restrict__ bk,
                                                 float* __restrict__ Qo,
                                                 float* __restrict__ Ko) {
    const int w = threadIdx.x >> 6, lane = threadIdx.x & 63;
    const int row = blockIdx.x * 4 + w;              // b*512 + f
    const bf16_t* y = Y + (size_t)row * SS;
    float qa[4] = {0.f, 0.f, 0.f, 0.f}, ka[4] = {0.f, 0.f, 0.f, 0.f};
#pragma unroll
    for (int c = 0; c < 4; ++c) {
        const int s = c * 512 + lane * 8;
        const bf16x8 yv = *(const bf16x8*)&y[s];
        float yf[8];
#pragma unroll
        for (int j = 0; j < 8; ++j) yf[j] = (float)yv[j];
#pragma unroll
        for (int r = 0; r < 4; ++r) {
            const float4 a0 = *(const float4*)&Wq[r * SS + s];
            const float4 a1 = *(const float4*)&Wq[r * SS + s + 4];
            const float4 c0 = *(const float4*)&Wk[r * SS + s];
            const float4 c1 = *(const float4*)&Wk[r * SS + s + 4];
            qa[r] += yf[0]*a0.x + yf[1]*a0.y + yf[2]*a0.z + yf[3]*a0.w
                   + yf[4]*a1.x + yf[5]*a1.y + yf[6]*a1.z + yf[7]*a1.w;
            ka[r] += yf[0]*c0.x + yf[1]*c0.y + yf[2]*c0.z + yf[3]*c0.w
                   + yf[4]*c1.x + yf[5]*c1.y + yf[6]*c1.z + yf[7]*c1.w;
        }
    }
#pragma unroll
    for (int off = 32; off > 0; off >>= 1) {
#pragma unroll
        for (int r = 0; r < 4; ++r) {
            qa[r] += __shfl_down(qa[r], off);
            ka[r] += __shfl_down(ka[r], off);
        }
    }
    if (lane == 0) {
#pragma unroll
        for (int r = 0; r < 4; ++r) {
            Qo[(size_t)row * 4 + r] = qa[r] + bq[r];
            Ko[(size_t)row * 4 + r] = ka[r] + bk[r];
        }
    }
}

// ----------------------------------- A = softmax(Q K^T / sqrt(4)), bf16 output
__global__ __launch_bounds__(256) void softmax_kernel(const float* __restrict__ Qo,
                                                      const float* __restrict__ Ko,
                                                      bf16_t* __restrict__ Aout) {
    const int w = threadIdx.x >> 6, lane = threadIdx.x & 63;
    const int row = blockIdx.x * 4 + w;              // b*512 + f
    const int b = row >> 9;
    const float4 q = *(const float4*)&Qo[(size_t)row * 4];
    const float* kb = Ko + (size_t)b * FF * 4;
    float sc[8];
#pragma unroll
    for (int j = 0; j < 8; ++j) {
        const float4 kv = *(const float4*)&kb[(lane * 8 + j) * 4];
        sc[j] = (q.x*kv.x + q.y*kv.y + q.z*kv.z + q.w*kv.w) * 0.5f;
    }
    float mx = sc[0];
#pragma unroll
    for (int j = 1; j < 8; ++j) mx = fmaxf(mx, sc[j]);
#pragma unroll
    for (int off = 32; off > 0; off >>= 1) mx = fmaxf(mx, __shfl_xor(mx, off));
    float sum = 0.f;
#pragma unroll
    for (int j = 0; j < 8; ++j) { sc[j] = __expf(sc[j] - mx); sum += sc[j]; }
#pragma unroll
    for (int off = 32; off > 0; off >>= 1) sum += __shfl_xor(sum, off);
    const float inv = 1.0f / sum;
    bf16x8 o;
#pragma unroll
    for (int j = 0; j < 8; ++j) o[j] = (bf16_t)(sc[j] * inv);
    *(bf16x8*)&Aout[(size_t)row * FF + lane * 8] = o;
}

// --------------------------------------------------------------- NT bf16 GEMM
// C[M][N] = A[M][K] * B[N][K]^T, batched. 256x256 tile, BK=64, 8 waves
// (2M x 4N, wave tile 128x64), 512 threads, 128 KiB LDS, 2-buffer ping-pong.
// FREE-RUN interior: stage all 8 next-tile loads at tile top, then whole-tile
// compute with NO barriers/waits/pins — compiler emits fine-grained lgkmcnt;
// the 2 waves/SIMD slip so one wave's ds_reads overlap the other's MFMAs.
// Intra-tile barriers are unnecessary: all reads hit buf[cur], all writes hit
// buf[oth]. Single boundary per tile: vmcnt(0)+s_barrier — drain is cheap
// because the drained loads were issued a full tile (~2300 cyc) earlier.
// FUSE: gemm2 writes out = x_norm + alpha*acc + (1+beta)*Vt directly (fp32);
// Vt IS the A operand, so it's a direct reload with identical indexing.
template<bool FUSE>
__global__ __launch_bounds__(512, 2) void gemm_nt_tile(
        const bf16_t* __restrict__ Abase, long long strideA, int lda,
        const bf16_t* __restrict__ Bbase, long long strideB, int ldb,
        bf16_t* __restrict__ Cbase, long long strideC, int ldc,
        int NTILES, const float* __restrict__ bias_m,
        const float* __restrict__ xp, const float* __restrict__ lwp,
        const float* __restrict__ lbp, const float* __restrict__ musig,
        const float* __restrict__ alphap, const float* __restrict__ betap,
        float* __restrict__ outp) {
    __shared__ __align__(16) bf16_t As[2][16384];   // [buf][kk*8192 + row*32 + swz]
    __shared__ __align__(16) bf16_t Bs[2][16384];   // total 128 KiB
    const int tid = threadIdx.x;
    const int w = tid >> 6, lane = tid & 63;

    // XCD-bijective swizzle (nwg = 256, 256 % 8 == 0)
    const int nchunk = gridDim.x >> 3;                               // 32
    const int wgid = (blockIdx.x & 7) * nchunk + (blockIdx.x >> 3);
    const int bz = wgid >> 4;            // batch
    const int rem = wgid & 15;
    const int m0 = (rem & 7) * 256, n0 = (rem >> 3) * 256;

    const bf16_t* A = Abase + (size_t)bz * (size_t)strideA;
    const bf16_t* B = Bbase + (size_t)bz * (size_t)strideB;
    bf16_t* C = Cbase + (size_t)bz * (size_t)strideC;
    const int wm = w >> 2, wn = w & 3;   // wave tile rows wm*128.., cols wn*64..

    // ---- staging: per half-matrix = 16 KiB = 2 insts/wave, 1 KiB each.
    const int rr0 = (w * 2 + 0) * 16 + (lane >> 2);
    const int rr1 = (w * 2 + 1) * 16 + (lane >> 2);
    const int sw0 = ((lane & 3) ^ ((rr0 >> 1) & 3)) * 8;
    const int sw1 = ((lane & 3) ^ ((rr1 >> 1) & 3)) * 8;
    const bf16_t* gA0 = A + (size_t)(m0 + rr0) * lda + sw0;
    const bf16_t* gA1 = A + (size_t)(m0 + rr1) * lda + sw1;
    const bf16_t* gB0 = B + (size_t)(n0 + rr0) * ldb + sw0;
    const bf16_t* gB1 = B + (size_t)(n0 + rr1) * ldb + sw1;
    const int d0 = (w * 2 + 0) * 512;   // wave-uniform LDS elem offset in half-region
    const int d1 = (w * 2 + 1) * 512;

#define STA(bi, h, ko) do {                                                          \
    __builtin_amdgcn_global_load_lds(                                                \
        (const __attribute__((address_space(1))) unsigned int*)(gA0 + (ko) + (h)*32),\
        (__attribute__((address_space(3))) unsigned int*)&As[bi][(h)*8192 + d0], 16, 0, 0); \
    __builtin_amdgcn_global_load_lds(                                                \
        (const __attribute__((address_space(1))) unsigned int*)(gA1 + (ko) + (h)*32),\
        (__attribute__((address_space(3))) unsigned int*)&As[bi][(h)*8192 + d1], 16, 0, 0); \
} while (0)
#define STB(bi, h, ko) do {                                                          \
    __builtin_amdgcn_global_load_lds(                                                \
        (const __attribute__((address_space(1))) unsigned int*)(gB0 + (ko) + (h)*32),\
        (__attribute__((address_space(3))) unsigned int*)&Bs[bi][(h)*8192 + d0], 16, 0, 0); \
    __builtin_amdgcn_global_load_lds(                                                \
        (const __attribute__((address_space(1))) unsigned int*)(gB1 + (ko) + (h)*32),\
        (__attribute__((address_space(3))) unsigned int*)&Bs[bi][(h)*8192 + d1], 16, 0, 0); \
} while (0)

    // ---- fragment ds_read offsets (same XOR on the read side; conflict-free)
    const int cs = lane >> 4;           // chunk-within-half 0..3
    int offA[2][8], offB[2][4];
#pragma unroll
    for (int kk = 0; kk < 2; ++kk) {
#pragma unroll
        for (int mt = 0; mt < 8; ++mt) {
            const int r = wm * 128 + mt * 16 + (lane & 15);
            offA[kk][mt] = kk * 8192 + r * 32 + ((cs ^ ((r >> 1) & 3)) << 3);
        }
#pragma unroll
        for (int nt = 0; nt < 4; ++nt) {
            const int r = wn * 64 + nt * 16 + (lane & 15);
            offB[kk][nt] = kk * 8192 + r * 32 + ((cs ^ ((r >> 1) & 3)) << 3);
        }
    }

    f32x4 acc[8][4] = {};
    const int mask = NTILES - 1;        // power of two

    // prologue: tile 0 into buf 0; wait landed
    STA(0, 0, 0); STB(0, 0, 0); STA(0, 1, 0); STB(0, 1, 0);
    asm volatile("s_waitcnt vmcnt(0)\n\ts_barrier" ::: "memory");

    for (int t = 0; t < NTILES; ++t) {
        const int oth = (t & 1) ^ 1;
        const int ko = ((t + 1) & mask) * 64;   // next tile k-offset (dummy at tail)
        // stage next tile (8 loads) — lands by this tile's end
        STA(oth, 0, ko); STB(oth, 0, ko); STA(oth, 1, ko); STB(oth, 1, ko);
        __builtin_amdgcn_sched_barrier(0);
        const bf16_t* as = As[t & 1];
        const bf16_t* bs = Bs[t & 1];
        // whole-tile compute: compiler-scheduled ds_reads + MFMAs (no pins)
#pragma unroll
        for (int kk = 0; kk < 2; ++kk) {
            bf16x8 bfr[4];
#pragma unroll
            for (int i = 0; i < 4; ++i) bfr[i] = *(const bf16x8*)&bs[offB[kk][i]];
#pragma unroll
            for (int mh = 0; mh < 2; ++mh) {
                bf16x8 af[4];
#pragma unroll
                for (int i = 0; i < 4; ++i) af[i] = *(const bf16x8*)&as[offA[kk][mh * 4 + i]];
#pragma unroll
                for (int i = 0; i < 4; ++i)
#pragma unroll
                    for (int nt = 0; nt < 4; ++nt)
                        acc[mh * 4 + i][nt] = __builtin_amdgcn_mfma_f32_16x16x32_bf16(
                            af[i], bfr[nt], acc[mh * 4 + i][nt], 0, 0, 0);
            }
        }
        // single boundary: next tile landed + all waves done reading cur
        asm volatile("s_waitcnt vmcnt(0)\n\ts_barrier" ::: "memory");
    }
#undef STA
#undef STB

    // Epilogue: C/D layout row=(lane>>4)*4+reg, col=lane&15 (verified)
    if constexpr (!FUSE) {
#pragma unroll
        for (int mt = 0; mt < 8; ++mt) {
#pragma unroll
            for (int r = 0; r < 4; ++r) {
                const int row = m0 + wm * 128 + mt * 16 + ((lane >> 4) << 2) + r;
                const float bm = bias_m ? bias_m[row] : 0.0f;
#pragma unroll
                for (int nt = 0; nt < 4; ++nt) {
                    const int col = n0 + wn * 64 + nt * 16 + (lane & 15);
                    C[(size_t)row * ldc + col] = (bf16_t)(acc[mt][nt][r] + bm);
                }
            }
        }
    } else {
        // out[b][row][col] = x_norm + alpha*acc + (1+beta)*Vt ; Vt == A operand
        const float mu = musig[bz], rs = musig[16 + bz];
        const float alpha = alphap[0];
        const float onepb = 1.0f + betap[0];
        const float* xb = xp + ((size_t)bz << 20);
        float* ob = outp + ((size_t)bz << 20);
#pragma unroll
        for (int mt = 0; mt < 8; ++mt) {
#pragma unroll
            for (int r = 0; r < 4; ++r) {
                const int row = m0 + wm * 128 + mt * 16 + ((lane >> 4) << 2) + r;
#pragma unroll
                for (int nt = 0; nt < 4; ++nt) {
                    const int col = n0 + wn * 64 + nt * 16 + (lane & 15);
                    const size_t idx = (size_t)row * FF + col;
                    const float xn = (xb[idx] - mu) * rs * lwp[idx] + lbp[idx];
                    const float v = (float)A[(size_t)row * lda + col];
                    ob[idx] = xn + alpha * acc[mt][nt][r] + onepb * v;
                }
            }
        }
    }
}

extern "C" void kernel_launch(void* const* d_in, const int* in_sizes, int n_in,
                              void* d_out, int out_size, void* d_ws, size_t ws_size,
                              hipStream_t stream) {
    const float* x   = (const float*)d_in[0];
    const float* Wq  = (const float*)d_in[1];
    const float* bq  = (const float*)d_in[2];
    const float* Wk  = (const float*)d_in[3];
    const float* bk  = (const float*)d_in[4];
    const float* Wv  = (const float*)d_in[5];
    const float* bv  = (const float*)d_in[6];
    const float* lw  = (const float*)d_in[7];
    const float* lb  = (const float*)d_in[8];
    const float* alp = (const float*)d_in[9];
    const float* bet = (const float*)d_in[10];
    float* out = (float*)d_out;

    char* ws = (char*)d_ws;
    float*  musig = (float*)(ws + 128);         // 32 f32: mu[16], rsig[16]
    float*  Qo    = (float*)(ws + 256);         // 16*512*4 f32 = 128 KiB
    float*  Ko    = (float*)(ws + 256 + 131072);
    bf16_t* Wvb   = (bf16_t*)(ws + 262400);     // 2048*2048 bf16 = 8 MiB
    bf16_t* Asm   = (bf16_t*)(ws + 8651008);    // 16*512*512 bf16 = 8 MiB
    float*  partials = (float*)(ws + 8651008);  // 2048 f32 — dead before Asm written
    bf16_t* Vt    = (bf16_t*)(ws + 17039616);   // 16*2048*512 bf16 = 32 MiB
    bf16_t* Y     = (bf16_t*)(ws + 50594048);   // 16*512*2048 bf16 = 32 MiB

    stats_kernel<<<dim3(64, 16), 256, 0, stream>>>(x, partials);
    finalize_stats<<<1, 256, 0, stream>>>(partials, musig);
    cast_wv<<<4096, 256, 0, stream>>>(Wv, Wvb);
    ynorm_kernel<<<dim3(16, 64, 16), 256, 0, stream>>>(x, lw, lb, musig, Y);
    qk_kernel<<<2048, 256, 0, stream>>>(Y, Wq, bq, Wk, bk, Qo, Ko);
    softmax_kernel<<<2048, 256, 0, stream>>>(Qo, Ko, Asm);
    // Vt[b,t,f] = sum_s Wv[t,s]*Y[b,f,s] + bv[t]   (M=2048,N=512,K=2048 -> 32 tiles)
    gemm_nt_tile<false><<<256, 512, 0, stream>>>(
        Wvb, 0, SS, Y, 1 << 20, SS, Vt, 1 << 20, FF, 32, bv,
        nullptr, nullptr, nullptr, nullptr, nullptr, nullptr, nullptr);
    // out[b,t,f] = x_norm + alpha*(Vt.Asm^T) + (1+beta)*Vt  (M=2048,N=512,K=512)
    gemm_nt_tile<true><<<256, 512, 0, stream>>>(
        Vt, 1 << 20, FF, Asm, FF * FF, FF, nullptr, 0, FF, 8, nullptr,
        x, lw, lb, musig, alp, bet, out);
}

// Round 8
// 196.964 us; speedup vs baseline: 1.0412x; 1.0412x over previous
//
#include <hip/hip_runtime.h>
#include <hip/hip_bf16.h>

// Problem constants
#define NB 16        // batches
#define SS 2048      // S
#define FF 512       // F

typedef __bf16 bf16_t;
typedef __bf16 bf16x8 __attribute__((ext_vector_type(8)));
typedef __bf16 bf16x4 __attribute__((ext_vector_type(4)));
typedef float  f32x4  __attribute__((ext_vector_type(4)));

// ---------------------------------------------------------------- LN stats
__global__ __launch_bounds__(256) void stats_kernel(const float* __restrict__ x,
                                                    float* __restrict__ partials) {
    const int b = blockIdx.y;
    const float* xb = x + ((size_t)b << 20) + (size_t)blockIdx.x * 16384;
    float s = 0.0f, ss = 0.0f;
#pragma unroll
    for (int i = 0; i < 16; ++i) {
        const float4 v = *(const float4*)&xb[(threadIdx.x + i * 256) * 4];
        s  += v.x + v.y + v.z + v.w;
        ss += v.x * v.x + v.y * v.y + v.z * v.z + v.w * v.w;
    }
#pragma unroll
    for (int off = 32; off > 0; off >>= 1) {
        s  += __shfl_down(s, off);
        ss += __shfl_down(ss, off);
    }
    __shared__ float ps[4], pss[4];
    const int w = threadIdx.x >> 6, lane = threadIdx.x & 63;
    if (lane == 0) { ps[w] = s; pss[w] = ss; }
    __syncthreads();
    if (threadIdx.x == 0) {
        partials[b * 64 + blockIdx.x]        = ps[0] + ps[1] + ps[2] + ps[3];
        partials[1024 + b * 64 + blockIdx.x] = pss[0] + pss[1] + pss[2] + pss[3];
    }
}

__global__ __launch_bounds__(256) void finalize_stats(const float* __restrict__ partials,
                                                      float* __restrict__ musig) {
    const int tid = threadIdx.x;          // 0..255
    const int b = tid >> 4, i = tid & 15;
    float s = 0.f, ss = 0.f;
#pragma unroll
    for (int j = 0; j < 4; ++j) {
        s  += partials[b * 64 + i * 4 + j];
        ss += partials[1024 + b * 64 + i * 4 + j];
    }
#pragma unroll
    for (int off = 8; off > 0; off >>= 1) {
        s  += __shfl_xor(s, off);
        ss += __shfl_xor(ss, off);
    }
    if (i == 0) {
        const float inv_n = 1.0f / 1048576.0f;
        const float mu  = s * inv_n;
        const float var = ss * inv_n - mu * mu;
        musig[b]      = mu;
        musig[16 + b] = rsqrtf(var + 1e-5f);
    }
}

// ------------------------------------------------- x_norm -> Y bf16 [b][f][s]
__global__ __launch_bounds__(256) void ynorm_kernel(const float* __restrict__ x,
                                                    const float* __restrict__ lw,
                                                    const float* __restrict__ lb,
                                                    const float* __restrict__ musig,
                                                    bf16_t* __restrict__ Y) {
    __shared__ bf16_t t[32][33];
    const int b = blockIdx.z;
    const int f0 = blockIdx.x * 32, s0 = blockIdx.y * 32;
    const float mu = musig[b], rs = musig[16 + b];
    const int c = threadIdx.x & 31, rb = threadIdx.x >> 5;   // rb in 0..7
#pragma unroll
    for (int i = 0; i < 4; ++i) {
        const int s_loc = rb + i * 8;
        const size_t idx = (size_t)(s0 + s_loc) * FF + f0 + c;
        const float yv = (x[((size_t)b << 20) + idx] - mu) * rs * lw[idx] + lb[idx];
        t[s_loc][c] = (bf16_t)yv;
    }
    __syncthreads();
#pragma unroll
    for (int i = 0; i < 4; ++i) {
        const int f_loc = rb + i * 8;
        Y[((size_t)b << 20) + (size_t)(f0 + f_loc) * SS + s0 + c] = t[c][f_loc];
    }
}

// ---------------------------------------------------------------- Wv -> bf16
__global__ __launch_bounds__(256) void cast_wv(const float* __restrict__ Wv,
                                               bf16_t* __restrict__ Wvb) {
    const size_t i = ((size_t)blockIdx.x * 256 + threadIdx.x) * 4;
    const float4 v = *(const float4*)&Wv[i];
    bf16x4 o;
    o[0] = (bf16_t)v.x; o[1] = (bf16_t)v.y; o[2] = (bf16_t)v.z; o[3] = (bf16_t)v.w;
    *(bf16x4*)&Wvb[i] = o;
}

// -------------------------------------------------- Q,K: [b*F] rows, R=4 each
__global__ __launch_bounds__(256) void qk_kernel(const bf16_t* __restrict__ Y,
                                                 const float* __restrict__ Wq,
                                                 const float* __restrict__ bq,
                                                 const float* __restrict__ Wk,
                                                 const float* __restrict__ bk,
                                                 float* __restrict__ Qo,
                                                 float* __restrict__ Ko) {
    const int w = threadIdx.x >> 6, lane = threadIdx.x & 63;
    const int row = blockIdx.x * 4 + w;              // b*512 + f
    const bf16_t* y = Y + (size_t)row * SS;
    float qa[4] = {0.f, 0.f, 0.f, 0.f}, ka[4] = {0.f, 0.f, 0.f, 0.f};
#pragma unroll
    for (int c = 0; c < 4; ++c) {
        const int s = c * 512 + lane * 8;
        const bf16x8 yv = *(const bf16x8*)&y[s];
        float yf[8];
#pragma unroll
        for (int j = 0; j < 8; ++j) yf[j] = (float)yv[j];
#pragma unroll
        for (int r = 0; r < 4; ++r) {
            const float4 a0 = *(const float4*)&Wq[r * SS + s];
            const float4 a1 = *(const float4*)&Wq[r * SS + s + 4];
            const float4 c0 = *(const float4*)&Wk[r * SS + s];
            const float4 c1 = *(const float4*)&Wk[r * SS + s + 4];
            qa[r] += yf[0]*a0.x + yf[1]*a0.y + yf[2]*a0.z + yf[3]*a0.w
                   + yf[4]*a1.x + yf[5]*a1.y + yf[6]*a1.z + yf[7]*a1.w;
            ka[r] += yf[0]*c0.x + yf[1]*c0.y + yf[2]*c0.z + yf[3]*c0.w
                   + yf[4]*c1.x + yf[5]*c1.y + yf[6]*c1.z + yf[7]*c1.w;
        }
    }
#pragma unroll
    for (int off = 32; off > 0; off >>= 1) {
#pragma unroll
        for (int r = 0; r < 4; ++r) {
            qa[r] += __shfl_down(qa[r], off);
            ka[r] += __shfl_down(ka[r], off);
        }
    }
    if (lane == 0) {
#pragma unroll
        for (int r = 0; r < 4; ++r) {
            Qo[(size_t)row * 4 + r] = qa[r] + bq[r];
            Ko[(size_t)row * 4 + r] = ka[r] + bk[r];
        }
    }
}

// ----------------------------------- A = softmax(Q K^T / sqrt(4)), bf16 output
__global__ __launch_bounds__(256) void softmax_kernel(const float* __restrict__ Qo,
                                                      const float* __restrict__ Ko,
                                                      bf16_t* __restrict__ Aout) {
    const int w = threadIdx.x >> 6, lane = threadIdx.x & 63;
    const int row = blockIdx.x * 4 + w;              // b*512 + f
    const int b = row >> 9;
    const float4 q = *(const float4*)&Qo[(size_t)row * 4];
    const float* kb = Ko + (size_t)b * FF * 4;
    float sc[8];
#pragma unroll
    for (int j = 0; j < 8; ++j) {
        const float4 kv = *(const float4*)&kb[(lane * 8 + j) * 4];
        sc[j] = (q.x*kv.x + q.y*kv.y + q.z*kv.z + q.w*kv.w) * 0.5f;
    }
    float mx = sc[0];
#pragma unroll
    for (int j = 1; j < 8; ++j) mx = fmaxf(mx, sc[j]);
#pragma unroll
    for (int off = 32; off > 0; off >>= 1) mx = fmaxf(mx, __shfl_xor(mx, off));
    float sum = 0.f;
#pragma unroll
    for (int j = 0; j < 8; ++j) { sc[j] = __expf(sc[j] - mx); sum += sc[j]; }
#pragma unroll
    for (int off = 32; off > 0; off >>= 1) sum += __shfl_xor(sum, off);
    const float inv = 1.0f / sum;
    bf16x8 o;
#pragma unroll
    for (int j = 0; j < 8; ++j) o[j] = (bf16_t)(sc[j] * inv);
    *(bf16x8*)&Aout[(size_t)row * FF + lane * 8] = o;
}

// --------------------------------------------------------------- NT bf16 GEMM
// C[M][N] = A[M][K] * B[N][K]^T, batched. 256x256 tile, BK=64, 8 waves
// (2M x 4N, wave tile 128x64), 512 threads, 128 KiB LDS, 2-buffer ping-pong.
// r6-proven 4-phase skeleton: per phase {ds_reads; stage; [vmcnt(4) one phase
// ahead]; s_barrier; lgkmcnt(0); setprio(1); 16 MFMA; setprio(0); s_barrier}.
// FUSE epilogue (gemm2): out = x_norm + alpha*acc + (1+beta)*Vt, routed
// through LDS for fully-coalesced float4 global traffic.
template<bool FUSE>
__global__ __launch_bounds__(512, 2) void gemm_nt_8phase(
        const bf16_t* __restrict__ Abase, long long strideA, int lda,
        const bf16_t* __restrict__ Bbase, long long strideB, int ldb,
        bf16_t* __restrict__ Cbase, long long strideC, int ldc,
        int NTILES, const float* __restrict__ bias_m,
        const float* __restrict__ xp, const float* __restrict__ lwp,
        const float* __restrict__ lbp, const float* __restrict__ musig,
        const float* __restrict__ alphap, const float* __restrict__ betap,
        float* __restrict__ outp) {
    __shared__ __align__(16) bf16_t As[2][16384];   // [buf][kk*8192 + row*32 + swz]
    __shared__ __align__(16) bf16_t Bs[2][16384];   // total 128 KiB
    const int tid = threadIdx.x;
    const int w = tid >> 6, lane = tid & 63;

    // XCD-bijective swizzle (nwg = 256, 256 % 8 == 0)
    const int nchunk = gridDim.x >> 3;                               // 32
    const int wgid = (blockIdx.x & 7) * nchunk + (blockIdx.x >> 3);
    const int bz = wgid >> 4;            // batch
    const int rem = wgid & 15;
    const int m0 = (rem & 7) * 256, n0 = (rem >> 3) * 256;

    const bf16_t* A = Abase + (size_t)bz * (size_t)strideA;
    const bf16_t* B = Bbase + (size_t)bz * (size_t)strideB;
    bf16_t* C = Cbase + (size_t)bz * (size_t)strideC;
    const int wm = w >> 2, wn = w & 3;   // wave tile rows wm*128.., cols wn*64..

    // ---- staging: per half-matrix = 16 KiB = 2 insts/wave, 1 KiB each.
    const int rr0 = (w * 2 + 0) * 16 + (lane >> 2);
    const int rr1 = (w * 2 + 1) * 16 + (lane >> 2);
    const int sw0 = ((lane & 3) ^ ((rr0 >> 1) & 3)) * 8;
    const int sw1 = ((lane & 3) ^ ((rr1 >> 1) & 3)) * 8;
    const bf16_t* gA0 = A + (size_t)(m0 + rr0) * lda + sw0;
    const bf16_t* gA1 = A + (size_t)(m0 + rr1) * lda + sw1;
    const bf16_t* gB0 = B + (size_t)(n0 + rr0) * ldb + sw0;
    const bf16_t* gB1 = B + (size_t)(n0 + rr1) * ldb + sw1;
    const int d0 = (w * 2 + 0) * 512;   // wave-uniform LDS elem offset in half-region
    const int d1 = (w * 2 + 1) * 512;

#define STA(bi, h, ko) do {                                                          \
    __builtin_amdgcn_global_load_lds(                                                \
        (const __attribute__((address_space(1))) unsigned int*)(gA0 + (ko) + (h)*32),\
        (__attribute__((address_space(3))) unsigned int*)&As[bi][(h)*8192 + d0], 16, 0, 0); \
    __builtin_amdgcn_global_load_lds(                                                \
        (const __attribute__((address_space(1))) unsigned int*)(gA1 + (ko) + (h)*32),\
        (__attribute__((address_space(3))) unsigned int*)&As[bi][(h)*8192 + d1], 16, 0, 0); \
} while (0)
#define STB(bi, h, ko) do {                                                          \
    __builtin_amdgcn_global_load_lds(                                                \
        (const __attribute__((address_space(1))) unsigned int*)(gB0 + (ko) + (h)*32),\
        (__attribute__((address_space(3))) unsigned int*)&Bs[bi][(h)*8192 + d0], 16, 0, 0); \
    __builtin_amdgcn_global_load_lds(                                                \
        (const __attribute__((address_space(1))) unsigned int*)(gB1 + (ko) + (h)*32),\
        (__attribute__((address_space(3))) unsigned int*)&Bs[bi][(h)*8192 + d1], 16, 0, 0); \
} while (0)

    // ---- fragment ds_read offsets (same XOR on the read side; conflict-free)
    const int cs = lane >> 4;           // chunk-within-half 0..3
    int offA[2][8], offB[2][4];
#pragma unroll
    for (int kk = 0; kk < 2; ++kk) {
#pragma unroll
        for (int mt = 0; mt < 8; ++mt) {
            const int r = wm * 128 + mt * 16 + (lane & 15);
            offA[kk][mt] = kk * 8192 + r * 32 + ((cs ^ ((r >> 1) & 3)) << 3);
        }
#pragma unroll
        for (int nt = 0; nt < 4; ++nt) {
            const int r = wn * 64 + nt * 16 + (lane & 15);
            offB[kk][nt] = kk * 8192 + r * 32 + ((cs ^ ((r >> 1) & 3)) << 3);
        }
    }

#define DS_A(kk, mh) do { _Pragma("unroll")                                   \
    for (int i = 0; i < 4; ++i) af[i] = *(const bf16x8*)&as[offA[kk][(mh)*4 + i]]; } while (0)
#define DS_B(kk) do { _Pragma("unroll")                                       \
    for (int i = 0; i < 4; ++i) bfr[i] = *(const bf16x8*)&bs[offB[kk][i]]; } while (0)
#define MFMA16(mh) do { _Pragma("unroll")                                     \
    for (int i = 0; i < 4; ++i) { _Pragma("unroll")                           \
        for (int nt = 0; nt < 4; ++nt)                                        \
            acc[(mh)*4 + i][nt] = __builtin_amdgcn_mfma_f32_16x16x32_bf16(    \
                af[i], bfr[nt], acc[(mh)*4 + i][nt], 0, 0, 0); } } while (0)
#define VM4   asm volatile("s_waitcnt vmcnt(4)" ::: "memory")
#define HBAR  __builtin_amdgcn_s_barrier()
#define LGKM0 do { asm volatile("s_waitcnt lgkmcnt(0)" ::: "memory");         \
                   __builtin_amdgcn_sched_barrier(0); } while (0)
#define SBAR  __builtin_amdgcn_sched_barrier(0)
#define PRIO1 __builtin_amdgcn_s_setprio(1)
#define PRIO0 __builtin_amdgcn_s_setprio(0)

    f32x4 acc[8][4] = {};
    const int mask = NTILES - 1;        // power of two

    // prologue: tile 0 into buf 0; force first half-tile landed
    STA(0, 0, 0); STB(0, 0, 0); STA(0, 1, 0); STB(0, 1, 0);
    VM4; HBAR;

    for (int t = 0; t < NTILES; ++t) {
        const int oth = (t & 1) ^ 1;
        const int ko = ((t + 1) & mask) * 64;   // next tile k-offset (dummy at tail)
        const bf16_t* as = As[t & 1];
        const bf16_t* bs = Bs[t & 1];
        bf16x8 af[4], bfr[4];
        // ---- P1 (kk0, m-lo): A-h0/B-h0 landed via prev P4's vmcnt+barrier
        DS_A(0, 0); DS_B(0); SBAR;
        STA(oth, 0, ko); SBAR;
        HBAR;
        LGKM0;
        PRIO1; MFMA16(0); PRIO0; SBAR;
        HBAR;
        // ---- P2 (kk0, m-hi): B kk0 frags reused
        DS_A(0, 1); SBAR;
        STB(oth, 0, ko); SBAR;
        VM4;                      // forces A-h1,B-h1 of tile t landed (P3 reads)
        HBAR;
        LGKM0;
        PRIO1; MFMA16(1); PRIO0; SBAR;
        HBAR;
        // ---- P3 (kk1, m-lo)
        DS_A(1, 0); DS_B(1); SBAR;
        STA(oth, 1, ko); SBAR;
        HBAR;
        LGKM0;
        PRIO1; MFMA16(0); PRIO0; SBAR;
        HBAR;
        // ---- P4 (kk1, m-hi)
        DS_A(1, 1); SBAR;
        STB(oth, 1, ko); SBAR;
        VM4;                      // forces A-h0,B-h0 of tile t+1 landed (next P1)
        HBAR;
        LGKM0;
        PRIO1; MFMA16(1); PRIO0; SBAR;
        HBAR;
    }
#undef STA
#undef STB
#undef DS_A
#undef DS_B
#undef MFMA16
#undef VM4
#undef HBAR
#undef LGKM0
#undef SBAR
#undef PRIO1
#undef PRIO0

    if constexpr (!FUSE) {
        // Epilogue: C/D layout row=(lane>>4)*4+reg, col=lane&15 (verified)
#pragma unroll
        for (int mt = 0; mt < 8; ++mt) {
#pragma unroll
            for (int r = 0; r < 4; ++r) {
                const int row = m0 + wm * 128 + mt * 16 + ((lane >> 4) << 2) + r;
                const float bm = bias_m ? bias_m[row] : 0.0f;
#pragma unroll
                for (int nt = 0; nt < 4; ++nt) {
                    const int col = n0 + wn * 64 + nt * 16 + (lane & 15);
                    C[(size_t)row * ldc + col] = (bf16_t)(acc[mt][nt][r] + bm);
                }
            }
        }
    } else {
        // Fused epilogue, coalesced via LDS:
        // out[b][row][col] = x_norm + alpha*acc + (1+beta)*Vt ; Vt == A operand.
        // Drain the in-flight dummy prefetch (it writes into As/Bs) first.
        asm volatile("s_waitcnt vmcnt(0)" ::: "memory");
        __syncthreads();
        float* lsc = (float*)&As[0][0];      // 32 KiB scratch: [32][256] f32
        const float mu = musig[bz], rs = musig[16 + bz];
        const float alpha = alphap[0];
        const float onepb = 1.0f + betap[0];
        const float* xb = xp + ((size_t)bz << 20);
        float* ob = outp + ((size_t)bz << 20);
        const int lrow = wm * 16 + ((lane >> 4) << 2);   // scatter local row base
        const int lcol = wn * 64 + (lane & 15);
        // gather mapping: 512 threads cover 32 rows x 256 cols
        const int gr = tid >> 4;             // 0..31 local row
        const int gc = (tid & 15) * 16;      // col base, 16 consecutive floats
        for (int mt = 0; mt < 8; ++mt) {
            // scatter acc[mt] -> lsc[32][256]
#pragma unroll
            for (int r = 0; r < 4; ++r)
#pragma unroll
                for (int nt = 0; nt < 4; ++nt)
                    lsc[(lrow + r) * 256 + lcol + nt * 16] = acc[mt][nt][r];
            __syncthreads();
            const int grow = m0 + (gr >> 4) * 128 + mt * 16 + (gr & 15);
            const size_t idx = (size_t)grow * FF + n0 + gc;
#pragma unroll
            for (int j = 0; j < 4; ++j) {
                const float4 av = *(const float4*)&lsc[gr * 256 + gc + j * 4];
                const float4 xv = *(const float4*)&xb[idx + j * 4];
                const float4 wv = *(const float4*)&lwp[idx + j * 4];
                const float4 bv4 = *(const float4*)&lbp[idx + j * 4];
                const bf16x4 vv = *(const bf16x4*)&A[idx + j * 4];   // Vt
                float4 o;
                o.x = (xv.x - mu) * rs * wv.x + bv4.x + alpha * av.x + onepb * (float)vv[0];
                o.y = (xv.y - mu) * rs * wv.y + bv4.y + alpha * av.y + onepb * (float)vv[1];
                o.z = (xv.z - mu) * rs * wv.z + bv4.z + alpha * av.z + onepb * (float)vv[2];
                o.w = (xv.w - mu) * rs * wv.w + bv4.w + alpha * av.w + onepb * (float)vv[3];
                *(float4*)&ob[idx + j * 4] = o;
            }
            __syncthreads();
        }
    }
}

extern "C" void kernel_launch(void* const* d_in, const int* in_sizes, int n_in,
                              void* d_out, int out_size, void* d_ws, size_t ws_size,
                              hipStream_t stream) {
    const float* x   = (const float*)d_in[0];
    const float* Wq  = (const float*)d_in[1];
    const float* bq  = (const float*)d_in[2];
    const float* Wk  = (const float*)d_in[3];
    const float* bk  = (const float*)d_in[4];
    const float* Wv  = (const float*)d_in[5];
    const float* bv  = (const float*)d_in[6];
    const float* lw  = (const float*)d_in[7];
    const float* lb  = (const float*)d_in[8];
    const float* alp = (const float*)d_in[9];
    const float* bet = (const float*)d_in[10];
    float* out = (float*)d_out;

    char* ws = (char*)d_ws;
    float*  musig = (float*)(ws + 128);         // 32 f32: mu[16], rsig[16]
    float*  Qo    = (float*)(ws + 256);         // 16*512*4 f32 = 128 KiB
    float*  Ko    = (float*)(ws + 256 + 131072);
    bf16_t* Wvb   = (bf16_t*)(ws + 262400);     // 2048*2048 bf16 = 8 MiB
    bf16_t* Asm   = (bf16_t*)(ws + 8651008);    // 16*512*512 bf16 = 8 MiB
    float*  partials = (float*)(ws + 8651008);  // 2048 f32 — dead before Asm written
    bf16_t* Vt    = (bf16_t*)(ws + 17039616);   // 16*2048*512 bf16 = 32 MiB
    bf16_t* Y     = (bf16_t*)(ws + 50594048);   // 16*512*2048 bf16 = 32 MiB

    stats_kernel<<<dim3(64, 16), 256, 0, stream>>>(x, partials);
    finalize_stats<<<1, 256, 0, stream>>>(partials, musig);
    cast_wv<<<4096, 256, 0, stream>>>(Wv, Wvb);
    ynorm_kernel<<<dim3(16, 64, 16), 256, 0, stream>>>(x, lw, lb, musig, Y);
    qk_kernel<<<2048, 256, 0, stream>>>(Y, Wq, bq, Wk, bk, Qo, Ko);
    softmax_kernel<<<2048, 256, 0, stream>>>(Qo, Ko, Asm);
    // Vt[b,t,f] = sum_s Wv[t,s]*Y[b,f,s] + bv[t]   (M=2048,N=512,K=2048 -> 32 tiles)
    gemm_nt_8phase<false><<<256, 512, 0, stream>>>(
        Wvb, 0, SS, Y, 1 << 20, SS, Vt, 1 << 20, FF, 32, bv,
        nullptr, nullptr, nullptr, nullptr, nullptr, nullptr, nullptr);
    // out[b,t,f] = x_norm + alpha*(Vt.Asm^T) + (1+beta)*Vt  (M=2048,N=512,K=512)
    gemm_nt_8phase<true><<<256, 512, 0, stream>>>(
        Vt, 1 << 20, FF, Asm, FF * FF, FF, nullptr, 0, FF, 8, nullptr,
        x, lw, lb, musig, alp, bet, out);
}

// Round 9
// 192.277 us; speedup vs baseline: 1.0666x; 1.0244x over previous
//
#include <hip/hip_runtime.h>
#include <hip/hip_bf16.h>

// Problem constants
#define NB 16        // batches
#define SS 2048      // S
#define FF 512       // F

typedef __bf16 bf16_t;
typedef __bf16 bf16x8 __attribute__((ext_vector_type(8)));
typedef __bf16 bf16x4 __attribute__((ext_vector_type(4)));
typedef float  f32x4  __attribute__((ext_vector_type(4)));

// ---------------------------------------------------------------- LN stats
__global__ __launch_bounds__(256) void stats_kernel(const float* __restrict__ x,
                                                    float* __restrict__ partials) {
    const int b = blockIdx.y;
    const float* xb = x + ((size_t)b << 20) + (size_t)blockIdx.x * 16384;
    float s = 0.0f, ss = 0.0f;
#pragma unroll
    for (int i = 0; i < 16; ++i) {
        const float4 v = *(const float4*)&xb[(threadIdx.x + i * 256) * 4];
        s  += v.x + v.y + v.z + v.w;
        ss += v.x * v.x + v.y * v.y + v.z * v.z + v.w * v.w;
    }
#pragma unroll
    for (int off = 32; off > 0; off >>= 1) {
        s  += __shfl_down(s, off);
        ss += __shfl_down(ss, off);
    }
    __shared__ float ps[4], pss[4];
    const int w = threadIdx.x >> 6, lane = threadIdx.x & 63;
    if (lane == 0) { ps[w] = s; pss[w] = ss; }
    __syncthreads();
    if (threadIdx.x == 0) {
        partials[b * 64 + blockIdx.x]        = ps[0] + ps[1] + ps[2] + ps[3];
        partials[1024 + b * 64 + blockIdx.x] = pss[0] + pss[1] + pss[2] + pss[3];
    }
}

__global__ __launch_bounds__(256) void finalize_stats(const float* __restrict__ partials,
                                                      float* __restrict__ musig) {
    const int tid = threadIdx.x;          // 0..255
    const int b = tid >> 4, i = tid & 15;
    float s = 0.f, ss = 0.f;
#pragma unroll
    for (int j = 0; j < 4; ++j) {
        s  += partials[b * 64 + i * 4 + j];
        ss += partials[1024 + b * 64 + i * 4 + j];
    }
#pragma unroll
    for (int off = 8; off > 0; off >>= 1) {
        s  += __shfl_xor(s, off);
        ss += __shfl_xor(ss, off);
    }
    if (i == 0) {
        const float inv_n = 1.0f / 1048576.0f;
        const float mu  = s * inv_n;
        const float var = ss * inv_n - mu * mu;
        musig[b]      = mu;
        musig[16 + b] = rsqrtf(var + 1e-5f);
    }
}

// ------------------------------------------------- x_norm -> Y bf16 [b][f][s]
// Vectorized: float4 reads along f, bf16x4 writes along s (G13).
__global__ __launch_bounds__(256) void ynorm_kernel(const float* __restrict__ x,
                                                    const float* __restrict__ lw,
                                                    const float* __restrict__ lb,
                                                    const float* __restrict__ musig,
                                                    bf16_t* __restrict__ Y) {
    __shared__ bf16_t t[32][36];         // [s][f], +4 pad
    const int b = blockIdx.z;
    const int f0 = blockIdx.x * 32, s0 = blockIdx.y * 32;
    const float mu = musig[b], rs = musig[16 + b];
    const int tid = threadIdx.x;
    {
        const int s_loc = tid >> 3, c4 = (tid & 7) * 4;
        const size_t idx = (size_t)(s0 + s_loc) * FF + f0 + c4;
        const float4 xv = *(const float4*)&x[((size_t)b << 20) + idx];
        const float4 wv = *(const float4*)&lw[idx];
        const float4 bv = *(const float4*)&lb[idx];
        t[s_loc][c4 + 0] = (bf16_t)((xv.x - mu) * rs * wv.x + bv.x);
        t[s_loc][c4 + 1] = (bf16_t)((xv.y - mu) * rs * wv.y + bv.y);
        t[s_loc][c4 + 2] = (bf16_t)((xv.z - mu) * rs * wv.z + bv.z);
        t[s_loc][c4 + 3] = (bf16_t)((xv.w - mu) * rs * wv.w + bv.w);
    }
    __syncthreads();
    {
        const int f_loc = tid >> 3, s4 = (tid & 7) * 4;
        bf16x4 o;
        o[0] = t[s4 + 0][f_loc];
        o[1] = t[s4 + 1][f_loc];
        o[2] = t[s4 + 2][f_loc];
        o[3] = t[s4 + 3][f_loc];
        *(bf16x4*)&Y[((size_t)b << 20) + (size_t)(f0 + f_loc) * SS + s0 + s4] = o;
    }
}

// ---------------------------------------------------------------- Wv -> bf16
__global__ __launch_bounds__(256) void cast_wv(const float* __restrict__ Wv,
                                               bf16_t* __restrict__ Wvb) {
    const size_t i = ((size_t)blockIdx.x * 256 + threadIdx.x) * 4;
    const float4 v = *(const float4*)&Wv[i];
    bf16x4 o;
    o[0] = (bf16_t)v.x; o[1] = (bf16_t)v.y; o[2] = (bf16_t)v.z; o[3] = (bf16_t)v.w;
    *(bf16x4*)&Wvb[i] = o;
}

// -------------------------------------------------- Q,K: [b*F] rows, R=4 each
__global__ __launch_bounds__(256) void qk_kernel(const bf16_t* __restrict__ Y,
                                                 const float* __restrict__ Wq,
                                                 const float* __restrict__ bq,
                                                 const float* __restrict__ Wk,
                                                 const float* __restrict__ bk,
                                                 float* __restrict__ Qo,
                                                 float* __restrict__ Ko) {
    const int w = threadIdx.x >> 6, lane = threadIdx.x & 63;
    const int row = blockIdx.x * 4 + w;              // b*512 + f
    const bf16_t* y = Y + (size_t)row * SS;
    float qa[4] = {0.f, 0.f, 0.f, 0.f}, ka[4] = {0.f, 0.f, 0.f, 0.f};
#pragma unroll
    for (int c = 0; c < 4; ++c) {
        const int s = c * 512 + lane * 8;
        const bf16x8 yv = *(const bf16x8*)&y[s];
        float yf[8];
#pragma unroll
        for (int j = 0; j < 8; ++j) yf[j] = (float)yv[j];
#pragma unroll
        for (int r = 0; r < 4; ++r) {
            const float4 a0 = *(const float4*)&Wq[r * SS + s];
            const float4 a1 = *(const float4*)&Wq[r * SS + s + 4];
            const float4 c0 = *(const float4*)&Wk[r * SS + s];
            const float4 c1 = *(const float4*)&Wk[r * SS + s + 4];
            qa[r] += yf[0]*a0.x + yf[1]*a0.y + yf[2]*a0.z + yf[3]*a0.w
                   + yf[4]*a1.x + yf[5]*a1.y + yf[6]*a1.z + yf[7]*a1.w;
            ka[r] += yf[0]*c0.x + yf[1]*c0.y + yf[2]*c0.z + yf[3]*c0.w
                   + yf[4]*c1.x + yf[5]*c1.y + yf[6]*c1.z + yf[7]*c1.w;
        }
    }
#pragma unroll
    for (int off = 32; off > 0; off >>= 1) {
#pragma unroll
        for (int r = 0; r < 4; ++r) {
            qa[r] += __shfl_down(qa[r], off);
            ka[r] += __shfl_down(ka[r], off);
        }
    }
    if (lane == 0) {
#pragma unroll
        for (int r = 0; r < 4; ++r) {
            Qo[(size_t)row * 4 + r] = qa[r] + bq[r];
            Ko[(size_t)row * 4 + r] = ka[r] + bk[r];
        }
    }
}

// ----------------------------------- A = softmax(Q K^T / sqrt(4)), bf16 output
__global__ __launch_bounds__(256) void softmax_kernel(const float* __restrict__ Qo,
                                                      const float* __restrict__ Ko,
                                                      bf16_t* __restrict__ Aout) {
    const int w = threadIdx.x >> 6, lane = threadIdx.x & 63;
    const int row = blockIdx.x * 4 + w;              // b*512 + f
    const int b = row >> 9;
    const float4 q = *(const float4*)&Qo[(size_t)row * 4];
    const float* kb = Ko + (size_t)b * FF * 4;
    float sc[8];
#pragma unroll
    for (int j = 0; j < 8; ++j) {
        const float4 kv = *(const float4*)&kb[(lane * 8 + j) * 4];
        sc[j] = (q.x*kv.x + q.y*kv.y + q.z*kv.z + q.w*kv.w) * 0.5f;
    }
    float mx = sc[0];
#pragma unroll
    for (int j = 1; j < 8; ++j) mx = fmaxf(mx, sc[j]);
#pragma unroll
    for (int off = 32; off > 0; off >>= 1) mx = fmaxf(mx, __shfl_xor(mx, off));
    float sum = 0.f;
#pragma unroll
    for (int j = 0; j < 8; ++j) { sc[j] = __expf(sc[j] - mx); sum += sc[j]; }
#pragma unroll
    for (int off = 32; off > 0; off >>= 1) sum += __shfl_xor(sum, off);
    const float inv = 1.0f / sum;
    bf16x8 o;
#pragma unroll
    for (int j = 0; j < 8; ++j) o[j] = (bf16_t)(sc[j] * inv);
    *(bf16x8*)&Aout[(size_t)row * FF + lane * 8] = o;
}

// --------------------------------------------------------------- NT bf16 GEMM
// C[M][N] = A[M][K] * B[N][K]^T, batched. 256x256 tile, BK=64, 8 waves
// (2M x 4N, wave tile 128x64), 512 threads, 128 KiB LDS, 2-buffer ping-pong.
// READ-AHEAD pipeline: each phase issues the NEXT cluster's ds_reads into a
// ping-pong register bank and waits with COUNTED lgkmcnt(4/8) (just-issued
// reads stay outstanding) -> ds_read latency hides under the previous MFMA
// cluster. Only 2 barriers/tile (P2/P4 entry), each paired with vmcnt(2)
// that forces exactly the 4 oldest loads = the half-tile the next cluster
// reads. Waves slip between barriers so one wave's reads overlap the other's
// MFMAs. Clusters: C1=(kk0,mlo) afA+bfrA; C2=(kk0,mhi) afB+bfrA;
// C3=(kk1,mlo) afA+bfrB; C4=(kk1,mhi) afB+bfrB.
template<bool FUSE>
__global__ __launch_bounds__(512, 2) void gemm_nt_pipe(
        const bf16_t* __restrict__ Abase, long long strideA, int lda,
        const bf16_t* __restrict__ Bbase, long long strideB, int ldb,
        bf16_t* __restrict__ Cbase, long long strideC, int ldc,
        int NTILES, const float* __restrict__ bias_m,
        const float* __restrict__ xp, const float* __restrict__ lwp,
        const float* __restrict__ lbp, const float* __restrict__ musig,
        const float* __restrict__ alphap, const float* __restrict__ betap,
        float* __restrict__ outp) {
    __shared__ __align__(16) bf16_t As[2][16384];   // [buf][kk*8192 + row*32 + swz]
    __shared__ __align__(16) bf16_t Bs[2][16384];   // total 128 KiB
    const int tid = threadIdx.x;
    const int w = tid >> 6, lane = tid & 63;

    // XCD-bijective swizzle (nwg = 256, 256 % 8 == 0)
    const int nchunk = gridDim.x >> 3;                               // 32
    const int wgid = (blockIdx.x & 7) * nchunk + (blockIdx.x >> 3);
    const int bz = wgid >> 4;            // batch
    const int rem = wgid & 15;
    const int m0 = (rem & 7) * 256, n0 = (rem >> 3) * 256;

    const bf16_t* A = Abase + (size_t)bz * (size_t)strideA;
    const bf16_t* B = Bbase + (size_t)bz * (size_t)strideB;
    bf16_t* C = Cbase + (size_t)bz * (size_t)strideC;
    const int wm = w >> 2, wn = w & 3;   // wave tile rows wm*128.., cols wn*64..

    // ---- staging: per half-matrix = 16 KiB = 2 insts/wave, 1 KiB each.
    const int rr0 = (w * 2 + 0) * 16 + (lane >> 2);
    const int rr1 = (w * 2 + 1) * 16 + (lane >> 2);
    const int sw0 = ((lane & 3) ^ ((rr0 >> 1) & 3)) * 8;
    const int sw1 = ((lane & 3) ^ ((rr1 >> 1) & 3)) * 8;
    const bf16_t* gA0 = A + (size_t)(m0 + rr0) * lda + sw0;
    const bf16_t* gA1 = A + (size_t)(m0 + rr1) * lda + sw1;
    const bf16_t* gB0 = B + (size_t)(n0 + rr0) * ldb + sw0;
    const bf16_t* gB1 = B + (size_t)(n0 + rr1) * ldb + sw1;
    const int d0 = (w * 2 + 0) * 512;   // wave-uniform LDS elem offset in half-region
    const int d1 = (w * 2 + 1) * 512;

#define STA(bi, h, ko) do {                                                          \
    __builtin_amdgcn_global_load_lds(                                                \
        (const __attribute__((address_space(1))) unsigned int*)(gA0 + (ko) + (h)*32),\
        (__attribute__((address_space(3))) unsigned int*)&As[bi][(h)*8192 + d0], 16, 0, 0); \
    __builtin_amdgcn_global_load_lds(                                                \
        (const __attribute__((address_space(1))) unsigned int*)(gA1 + (ko) + (h)*32),\
        (__attribute__((address_space(3))) unsigned int*)&As[bi][(h)*8192 + d1], 16, 0, 0); \
} while (0)
#define STB(bi, h, ko) do {                                                          \
    __builtin_amdgcn_global_load_lds(                                                \
        (const __attribute__((address_space(1))) unsigned int*)(gB0 + (ko) + (h)*32),\
        (__attribute__((address_space(3))) unsigned int*)&Bs[bi][(h)*8192 + d0], 16, 0, 0); \
    __builtin_amdgcn_global_load_lds(                                                \
        (const __attribute__((address_space(1))) unsigned int*)(gB1 + (ko) + (h)*32),\
        (__attribute__((address_space(3))) unsigned int*)&Bs[bi][(h)*8192 + d1], 16, 0, 0); \
} while (0)

    // ---- fragment ds_read offsets (same XOR on the read side; conflict-free)
    const int cs = lane >> 4;           // chunk-within-half 0..3
    int offA[2][8], offB[2][4];
#pragma unroll
    for (int kk = 0; kk < 2; ++kk) {
#pragma unroll
        for (int mt = 0; mt < 8; ++mt) {
            const int r = wm * 128 + mt * 16 + (lane & 15);
            offA[kk][mt] = kk * 8192 + r * 32 + ((cs ^ ((r >> 1) & 3)) << 3);
        }
#pragma unroll
        for (int nt = 0; nt < 4; ++nt) {
            const int r = wn * 64 + nt * 16 + (lane & 15);
            offB[kk][nt] = kk * 8192 + r * 32 + ((cs ^ ((r >> 1) & 3)) << 3);
        }
    }

#define RD_A(dst, base, kk, mh) do { _Pragma("unroll")                        \
    for (int i = 0; i < 4; ++i) dst[i] = *(const bf16x8*)&(base)[offA[kk][(mh)*4 + i]]; } while (0)
#define RD_B(dst, base, kk) do { _Pragma("unroll")                            \
    for (int i = 0; i < 4; ++i) dst[i] = *(const bf16x8*)&(base)[offB[kk][i]]; } while (0)
#define MFMA16X(af, bfr, mh) do { _Pragma("unroll")                           \
    for (int i = 0; i < 4; ++i) { _Pragma("unroll")                           \
        for (int nt = 0; nt < 4; ++nt)                                        \
            acc[(mh)*4 + i][nt] = __builtin_amdgcn_mfma_f32_16x16x32_bf16(    \
                af[i], bfr[nt], acc[(mh)*4 + i][nt], 0, 0, 0); } } while (0)
#define VMC(n) asm volatile("s_waitcnt vmcnt(" #n ")" ::: "memory")
#define HBAR  __builtin_amdgcn_s_barrier()
#define LGKM(n) do { asm volatile("s_waitcnt lgkmcnt(" #n ")" ::: "memory");  \
                     __builtin_amdgcn_sched_barrier(0); } while (0)
#define SBAR  __builtin_amdgcn_sched_barrier(0)
#define PRIO1 __builtin_amdgcn_s_setprio(1)
#define PRIO0 __builtin_amdgcn_s_setprio(0)

    f32x4 acc[8][4] = {};
    bf16x8 afA[4], afB[4], bfrA[4], bfrB[4];
    const int mask = NTILES - 1;        // power of two

    // prologue: tile 0 into buf 0; force h0 landed; issue C1 reads
    STA(0, 0, 0); STB(0, 0, 0); STA(0, 1, 0); STB(0, 1, 0);
    VMC(4); HBAR;
    RD_A(afA, As[0], 0, 0); RD_B(bfrA, Bs[0], 0);

    for (int t = 0; t < NTILES; ++t) {
        const int cur = t & 1, oth = cur ^ 1;
        const int ko = ((t + 1) & mask) * 64;   // next tile k-offset (dummy at tail)
        const bf16_t* as  = As[cur];
        const bf16_t* bs  = Bs[cur];
        const bf16_t* asn = As[oth];
        const bf16_t* bsn = Bs[oth];
        // ---- P1: consume C1 -> acc[0..3]; issue C2 reads (4)
        RD_A(afB, as, 0, 1); SBAR;
        STA(oth, 0, ko); SBAR;
        LGKM(4);
        PRIO1; MFMA16X(afA, bfrA, 0); PRIO0; SBAR;
        // ---- P2: h1 of tile t landed-check; consume C2 -> acc[4..7]; issue C3 (8)
        VMC(2); HBAR;
        RD_A(afA, as, 1, 0); RD_B(bfrB, bs, 1); SBAR;
        STB(oth, 0, ko); SBAR;
        LGKM(8);
        PRIO1; MFMA16X(afB, bfrA, 1); PRIO0; SBAR;
        // ---- P3: consume C3 -> acc[0..3]; issue C4 (4)
        RD_A(afB, as, 1, 1); SBAR;
        STA(oth, 1, ko); SBAR;
        LGKM(4);
        PRIO1; MFMA16X(afA, bfrB, 0); PRIO0; SBAR;
        // ---- P4: h0 of tile t+1 landed-check; consume C4; issue next C1 (8)
        VMC(2); HBAR;
        RD_A(afA, asn, 0, 0); RD_B(bfrA, bsn, 0); SBAR;
        STB(oth, 1, ko); SBAR;
        LGKM(8);
        PRIO1; MFMA16X(afB, bfrB, 1); PRIO0; SBAR;
    }
#undef STA
#undef STB
#undef RD_A
#undef RD_B
#undef MFMA16X
#undef VMC
#undef HBAR
#undef LGKM
#undef SBAR
#undef PRIO1
#undef PRIO0

    if constexpr (!FUSE) {
        // Epilogue: C/D layout row=(lane>>4)*4+reg, col=lane&15 (verified)
#pragma unroll
        for (int mt = 0; mt < 8; ++mt) {
#pragma unroll
            for (int r = 0; r < 4; ++r) {
                const int row = m0 + wm * 128 + mt * 16 + ((lane >> 4) << 2) + r;
                const float bm = bias_m ? bias_m[row] : 0.0f;
#pragma unroll
                for (int nt = 0; nt < 4; ++nt) {
                    const int col = n0 + wn * 64 + nt * 16 + (lane & 15);
                    C[(size_t)row * ldc + col] = (bf16_t)(acc[mt][nt][r] + bm);
                }
            }
        }
    } else {
        // Fused epilogue, coalesced via LDS:
        // out[b][row][col] = x_norm + alpha*acc + (1+beta)*Vt ; Vt == A operand.
        asm volatile("s_waitcnt vmcnt(0) lgkmcnt(0)" ::: "memory");
        __syncthreads();
        float* lsc = (float*)&As[0][0];      // 32 KiB scratch: [32][256] f32
        const float mu = musig[bz], rs = musig[16 + bz];
        const float alpha = alphap[0];
        const float onepb = 1.0f + betap[0];
        const float* xb = xp + ((size_t)bz << 20);
        float* ob = outp + ((size_t)bz << 20);
        const int lrow = wm * 16 + ((lane >> 4) << 2);   // scatter local row base
        const int lcol = wn * 64 + (lane & 15);
        const int gr = tid >> 4;             // 0..31 local row
        const int gc = (tid & 15) * 16;      // col base, 16 consecutive floats
        for (int mt = 0; mt < 8; ++mt) {
#pragma unroll
            for (int r = 0; r < 4; ++r)
#pragma unroll
                for (int nt = 0; nt < 4; ++nt)
                    lsc[(lrow + r) * 256 + lcol + nt * 16] = acc[mt][nt][r];
            __syncthreads();
            const int grow = m0 + (gr >> 4) * 128 + mt * 16 + (gr & 15);
            const size_t idx = (size_t)grow * FF + n0 + gc;
#pragma unroll
            for (int j = 0; j < 4; ++j) {
                const float4 av = *(const float4*)&lsc[gr * 256 + gc + j * 4];
                const float4 xv = *(const float4*)&xb[idx + j * 4];
                const float4 wv = *(const float4*)&lwp[idx + j * 4];
                const float4 bv4 = *(const float4*)&lbp[idx + j * 4];
                const bf16x4 vv = *(const bf16x4*)&A[idx + j * 4];   // Vt
                float4 o;
                o.x = (xv.x - mu) * rs * wv.x + bv4.x + alpha * av.x + onepb * (float)vv[0];
                o.y = (xv.y - mu) * rs * wv.y + bv4.y + alpha * av.y + onepb * (float)vv[1];
                o.z = (xv.z - mu) * rs * wv.z + bv4.z + alpha * av.z + onepb * (float)vv[2];
                o.w = (xv.w - mu) * rs * wv.w + bv4.w + alpha * av.w + onepb * (float)vv[3];
                *(float4*)&ob[idx + j * 4] = o;
            }
            __syncthreads();
        }
    }
}

extern "C" void kernel_launch(void* const* d_in, const int* in_sizes, int n_in,
                              void* d_out, int out_size, void* d_ws, size_t ws_size,
                              hipStream_t stream) {
    const float* x   = (const float*)d_in[0];
    const float* Wq  = (const float*)d_in[1];
    const float* bq  = (const float*)d_in[2];
    const float* Wk  = (const float*)d_in[3];
    const float* bk  = (const float*)d_in[4];
    const float* Wv  = (const float*)d_in[5];
    const float* bv  = (const float*)d_in[6];
    const float* lw  = (const float*)d_in[7];
    const float* lb  = (const float*)d_in[8];
    const float* alp = (const float*)d_in[9];
    const float* bet = (const float*)d_in[10];
    float* out = (float*)d_out;

    char* ws = (char*)d_ws;
    float*  musig = (float*)(ws + 128);         // 32 f32: mu[16], rsig[16]
    float*  Qo    = (float*)(ws + 256);         // 16*512*4 f32 = 128 KiB
    float*  Ko    = (float*)(ws + 256 + 131072);
    bf16_t* Wvb   = (bf16_t*)(ws + 262400);     // 2048*2048 bf16 = 8 MiB
    bf16_t* Asm   = (bf16_t*)(ws + 8651008);    // 16*512*512 bf16 = 8 MiB
    float*  partials = (float*)(ws + 8651008);  // 2048 f32 — dead before Asm written
    bf16_t* Vt    = (bf16_t*)(ws + 17039616);   // 16*2048*512 bf16 = 32 MiB
    bf16_t* Y     = (bf16_t*)(ws + 50594048);   // 16*512*2048 bf16 = 32 MiB

    stats_kernel<<<dim3(64, 16), 256, 0, stream>>>(x, partials);
    finalize_stats<<<1, 256, 0, stream>>>(partials, musig);
    cast_wv<<<4096, 256, 0, stream>>>(Wv, Wvb);
    ynorm_kernel<<<dim3(16, 64, 16), 256, 0, stream>>>(x, lw, lb, musig, Y);
    qk_kernel<<<2048, 256, 0, stream>>>(Y, Wq, bq, Wk, bk, Qo, Ko);
    softmax_kernel<<<2048, 256, 0, stream>>>(Qo, Ko, Asm);
    // Vt[b,t,f] = sum_s Wv[t,s]*Y[b,f,s] + bv[t]   (M=2048,N=512,K=2048 -> 32 tiles)
    gemm_nt_pipe<false><<<256, 512, 0, stream>>>(
        Wvb, 0, SS, Y, 1 << 20, SS, Vt, 1 << 20, FF, 32, bv,
        nullptr, nullptr, nullptr, nullptr, nullptr, nullptr, nullptr);
    // out[b,t,f] = x_norm + alpha*(Vt.Asm^T) + (1+beta)*Vt  (M=2048,N=512,K=512)
    gemm_nt_pipe<true><<<256, 512, 0, stream>>>(
        Vt, 1 << 20, FF, Asm, FF * FF, FF, nullptr, 0, FF, 8, nullptr,
        x, lw, lb, musig, alp, bet, out);
}

// Round 10
// 181.832 us; speedup vs baseline: 1.1278x; 1.0574x over previous
//
#include <hip/hip_runtime.h>
#include <hip/hip_bf16.h>

// Problem constants
#define NB 16        // batches
#define SS 2048      // S
#define FF 512       // F

typedef __bf16 bf16_t;
typedef __bf16 bf16x8 __attribute__((ext_vector_type(8)));
typedef __bf16 bf16x4 __attribute__((ext_vector_type(4)));
typedef float  f32x4  __attribute__((ext_vector_type(4)));

// ---------------------------------------------------------------- LN stats
__global__ __launch_bounds__(256) void stats_kernel(const float* __restrict__ x,
                                                    float* __restrict__ partials) {
    const int b = blockIdx.y;
    const float* xb = x + ((size_t)b << 20) + (size_t)blockIdx.x * 16384;
    float s = 0.0f, ss = 0.0f;
#pragma unroll
    for (int i = 0; i < 16; ++i) {
        const float4 v = *(const float4*)&xb[(threadIdx.x + i * 256) * 4];
        s  += v.x + v.y + v.z + v.w;
        ss += v.x * v.x + v.y * v.y + v.z * v.z + v.w * v.w;
    }
#pragma unroll
    for (int off = 32; off > 0; off >>= 1) {
        s  += __shfl_down(s, off);
        ss += __shfl_down(ss, off);
    }
    __shared__ float ps[4], pss[4];
    const int w = threadIdx.x >> 6, lane = threadIdx.x & 63;
    if (lane == 0) { ps[w] = s; pss[w] = ss; }
    __syncthreads();
    if (threadIdx.x == 0) {
        partials[b * 64 + blockIdx.x]        = ps[0] + ps[1] + ps[2] + ps[3];
        partials[1024 + b * 64 + blockIdx.x] = pss[0] + pss[1] + pss[2] + pss[3];
    }
}

__global__ __launch_bounds__(256) void finalize_stats(const float* __restrict__ partials,
                                                      float* __restrict__ musig) {
    const int tid = threadIdx.x;          // 0..255
    const int b = tid >> 4, i = tid & 15;
    float s = 0.f, ss = 0.f;
#pragma unroll
    for (int j = 0; j < 4; ++j) {
        s  += partials[b * 64 + i * 4 + j];
        ss += partials[1024 + b * 64 + i * 4 + j];
    }
#pragma unroll
    for (int off = 8; off > 0; off >>= 1) {
        s  += __shfl_xor(s, off);
        ss += __shfl_xor(ss, off);
    }
    if (i == 0) {
        const float inv_n = 1.0f / 1048576.0f;
        const float mu  = s * inv_n;
        const float var = ss * inv_n - mu * mu;
        musig[b]      = mu;
        musig[16 + b] = rsqrtf(var + 1e-5f);
    }
}

// ------------------------------------------------- x_norm -> Y bf16 [b][f][s]
// Also (optionally) writes Xn = x_norm bf16 in [b][s][f] for the fused epilogue.
__global__ __launch_bounds__(256) void ynorm_kernel(const float* __restrict__ x,
                                                    const float* __restrict__ lw,
                                                    const float* __restrict__ lb,
                                                    const float* __restrict__ musig,
                                                    bf16_t* __restrict__ Y,
                                                    bf16_t* __restrict__ Xn) {
    __shared__ bf16_t t[32][36];         // [s][f], +4 pad
    const int b = blockIdx.z;
    const int f0 = blockIdx.x * 32, s0 = blockIdx.y * 32;
    const float mu = musig[b], rs = musig[16 + b];
    const int tid = threadIdx.x;
    {
        const int s_loc = tid >> 3, c4 = (tid & 7) * 4;
        const size_t idx = (size_t)(s0 + s_loc) * FF + f0 + c4;
        const float4 xv = *(const float4*)&x[((size_t)b << 20) + idx];
        const float4 wv = *(const float4*)&lw[idx];
        const float4 bv = *(const float4*)&lb[idx];
        bf16x4 o;
        o[0] = (bf16_t)((xv.x - mu) * rs * wv.x + bv.x);
        o[1] = (bf16_t)((xv.y - mu) * rs * wv.y + bv.y);
        o[2] = (bf16_t)((xv.z - mu) * rs * wv.z + bv.z);
        o[3] = (bf16_t)((xv.w - mu) * rs * wv.w + bv.w);
        t[s_loc][c4 + 0] = o[0];
        t[s_loc][c4 + 1] = o[1];
        t[s_loc][c4 + 2] = o[2];
        t[s_loc][c4 + 3] = o[3];
        if (Xn) *(bf16x4*)&Xn[((size_t)b << 20) + idx] = o;
    }
    __syncthreads();
    {
        const int f_loc = tid >> 3, s4 = (tid & 7) * 4;
        bf16x4 o;
        o[0] = t[s4 + 0][f_loc];
        o[1] = t[s4 + 1][f_loc];
        o[2] = t[s4 + 2][f_loc];
        o[3] = t[s4 + 3][f_loc];
        *(bf16x4*)&Y[((size_t)b << 20) + (size_t)(f0 + f_loc) * SS + s0 + s4] = o;
    }
}

// ---------------------------------------------------------------- Wv -> bf16
__global__ __launch_bounds__(256) void cast_wv(const float* __restrict__ Wv,
                                               bf16_t* __restrict__ Wvb) {
    const size_t i = ((size_t)blockIdx.x * 256 + threadIdx.x) * 4;
    const float4 v = *(const float4*)&Wv[i];
    bf16x4 o;
    o[0] = (bf16_t)v.x; o[1] = (bf16_t)v.y; o[2] = (bf16_t)v.z; o[3] = (bf16_t)v.w;
    *(bf16x4*)&Wvb[i] = o;
}

// -------------------------------------------------- Q,K: [b*F] rows, R=4 each
__global__ __launch_bounds__(256) void qk_kernel(const bf16_t* __restrict__ Y,
                                                 const float* __restrict__ Wq,
                                                 const float* __restrict__ bq,
                                                 const float* __restrict__ Wk,
                                                 const float* __restrict__ bk,
                                                 float* __restrict__ Qo,
                                                 float* __restrict__ Ko) {
    const int w = threadIdx.x >> 6, lane = threadIdx.x & 63;
    const int row = blockIdx.x * 4 + w;              // b*512 + f
    const bf16_t* y = Y + (size_t)row * SS;
    float qa[4] = {0.f, 0.f, 0.f, 0.f}, ka[4] = {0.f, 0.f, 0.f, 0.f};
#pragma unroll
    for (int c = 0; c < 4; ++c) {
        const int s = c * 512 + lane * 8;
        const bf16x8 yv = *(const bf16x8*)&y[s];
        float yf[8];
#pragma unroll
        for (int j = 0; j < 8; ++j) yf[j] = (float)yv[j];
#pragma unroll
        for (int r = 0; r < 4; ++r) {
            const float4 a0 = *(const float4*)&Wq[r * SS + s];
            const float4 a1 = *(const float4*)&Wq[r * SS + s + 4];
            const float4 c0 = *(const float4*)&Wk[r * SS + s];
            const float4 c1 = *(const float4*)&Wk[r * SS + s + 4];
            qa[r] += yf[0]*a0.x + yf[1]*a0.y + yf[2]*a0.z + yf[3]*a0.w
                   + yf[4]*a1.x + yf[5]*a1.y + yf[6]*a1.z + yf[7]*a1.w;
            ka[r] += yf[0]*c0.x + yf[1]*c0.y + yf[2]*c0.z + yf[3]*c0.w
                   + yf[4]*c1.x + yf[5]*c1.y + yf[6]*c1.z + yf[7]*c1.w;
        }
    }
#pragma unroll
    for (int off = 32; off > 0; off >>= 1) {
#pragma unroll
        for (int r = 0; r < 4; ++r) {
            qa[r] += __shfl_down(qa[r], off);
            ka[r] += __shfl_down(ka[r], off);
        }
    }
    if (lane == 0) {
#pragma unroll
        for (int r = 0; r < 4; ++r) {
            Qo[(size_t)row * 4 + r] = qa[r] + bq[r];
            Ko[(size_t)row * 4 + r] = ka[r] + bk[r];
        }
    }
}

// ----------------------------------- A = softmax(Q K^T / sqrt(4)), bf16 output
__global__ __launch_bounds__(256) void softmax_kernel(const float* __restrict__ Qo,
                                                      const float* __restrict__ Ko,
                                                      bf16_t* __restrict__ Aout) {
    const int w = threadIdx.x >> 6, lane = threadIdx.x & 63;
    const int row = blockIdx.x * 4 + w;              // b*512 + f
    const int b = row >> 9;
    const float4 q = *(const float4*)&Qo[(size_t)row * 4];
    const float* kb = Ko + (size_t)b * FF * 4;
    float sc[8];
#pragma unroll
    for (int j = 0; j < 8; ++j) {
        const float4 kv = *(const float4*)&kb[(lane * 8 + j) * 4];
        sc[j] = (q.x*kv.x + q.y*kv.y + q.z*kv.z + q.w*kv.w) * 0.5f;
    }
    float mx = sc[0];
#pragma unroll
    for (int j = 1; j < 8; ++j) mx = fmaxf(mx, sc[j]);
#pragma unroll
    for (int off = 32; off > 0; off >>= 1) mx = fmaxf(mx, __shfl_xor(mx, off));
    float sum = 0.f;
#pragma unroll
    for (int j = 0; j < 8; ++j) { sc[j] = __expf(sc[j] - mx); sum += sc[j]; }
#pragma unroll
    for (int off = 32; off > 0; off >>= 1) sum += __shfl_xor(sum, off);
    const float inv = 1.0f / sum;
    bf16x8 o;
#pragma unroll
    for (int j = 0; j < 8; ++j) o[j] = (bf16_t)(sc[j] * inv);
    *(bf16x8*)&Aout[(size_t)row * FF + lane * 8] = o;
}

// --------------------------------------------------------------- NT bf16 GEMM
// r9-proven read-ahead pipeline (see r9 comments). EPI: 0 = plain bf16 C-write;
// 1 = fused epilogue reading x/lw/lb fp32; 2 = fused epilogue reading Xn bf16.
template<int EPI>
__device__ __forceinline__ void gemm_impl(
        const bf16_t* __restrict__ Abase, long long strideA, int lda,
        const bf16_t* __restrict__ Bbase, long long strideB, int ldb,
        bf16_t* __restrict__ Cbase, long long strideC, int ldc,
        int NTILES, const float* __restrict__ bias_m,
        const float* __restrict__ xp, const float* __restrict__ lwp,
        const float* __restrict__ lbp, const bf16_t* __restrict__ xnp,
        const float* __restrict__ musig,
        const float* __restrict__ alphap, const float* __restrict__ betap,
        float* __restrict__ outp) {
    __shared__ __align__(16) bf16_t As[2][16384];   // [buf][kk*8192 + row*32 + swz]
    __shared__ __align__(16) bf16_t Bs[2][16384];   // total 128 KiB
    const int tid = threadIdx.x;
    const int w = tid >> 6, lane = tid & 63;

    // XCD-bijective swizzle (nwg = 256, 256 % 8 == 0)
    const int nchunk = gridDim.x >> 3;                               // 32
    const int wgid = (blockIdx.x & 7) * nchunk + (blockIdx.x >> 3);
    const int bz = wgid >> 4;            // batch
    const int rem = wgid & 15;
    const int m0 = (rem & 7) * 256, n0 = (rem >> 3) * 256;

    const bf16_t* A = Abase + (size_t)bz * (size_t)strideA;
    const bf16_t* B = Bbase + (size_t)bz * (size_t)strideB;
    bf16_t* C = Cbase + (size_t)bz * (size_t)strideC;
    const int wm = w >> 2, wn = w & 3;   // wave tile rows wm*128.., cols wn*64..

    const int rr0 = (w * 2 + 0) * 16 + (lane >> 2);
    const int rr1 = (w * 2 + 1) * 16 + (lane >> 2);
    const int sw0 = ((lane & 3) ^ ((rr0 >> 1) & 3)) * 8;
    const int sw1 = ((lane & 3) ^ ((rr1 >> 1) & 3)) * 8;
    const bf16_t* gA0 = A + (size_t)(m0 + rr0) * lda + sw0;
    const bf16_t* gA1 = A + (size_t)(m0 + rr1) * lda + sw1;
    const bf16_t* gB0 = B + (size_t)(n0 + rr0) * ldb + sw0;
    const bf16_t* gB1 = B + (size_t)(n0 + rr1) * ldb + sw1;
    const int d0 = (w * 2 + 0) * 512;
    const int d1 = (w * 2 + 1) * 512;

#define STA(bi, h, ko) do {                                                          \
    __builtin_amdgcn_global_load_lds(                                                \
        (const __attribute__((address_space(1))) unsigned int*)(gA0 + (ko) + (h)*32),\
        (__attribute__((address_space(3))) unsigned int*)&As[bi][(h)*8192 + d0], 16, 0, 0); \
    __builtin_amdgcn_global_load_lds(                                                \
        (const __attribute__((address_space(1))) unsigned int*)(gA1 + (ko) + (h)*32),\
        (__attribute__((address_space(3))) unsigned int*)&As[bi][(h)*8192 + d1], 16, 0, 0); \
} while (0)
#define STB(bi, h, ko) do {                                                          \
    __builtin_amdgcn_global_load_lds(                                                \
        (const __attribute__((address_space(1))) unsigned int*)(gB0 + (ko) + (h)*32),\
        (__attribute__((address_space(3))) unsigned int*)&Bs[bi][(h)*8192 + d0], 16, 0, 0); \
    __builtin_amdgcn_global_load_lds(                                                \
        (const __attribute__((address_space(1))) unsigned int*)(gB1 + (ko) + (h)*32),\
        (__attribute__((address_space(3))) unsigned int*)&Bs[bi][(h)*8192 + d1], 16, 0, 0); \
} while (0)

    const int cs = lane >> 4;
    int offA[2][8], offB[2][4];
#pragma unroll
    for (int kk = 0; kk < 2; ++kk) {
#pragma unroll
        for (int mt = 0; mt < 8; ++mt) {
            const int r = wm * 128 + mt * 16 + (lane & 15);
            offA[kk][mt] = kk * 8192 + r * 32 + ((cs ^ ((r >> 1) & 3)) << 3);
        }
#pragma unroll
        for (int nt = 0; nt < 4; ++nt) {
            const int r = wn * 64 + nt * 16 + (lane & 15);
            offB[kk][nt] = kk * 8192 + r * 32 + ((cs ^ ((r >> 1) & 3)) << 3);
        }
    }

#define RD_A(dst, base, kk, mh) do { _Pragma("unroll")                        \
    for (int i = 0; i < 4; ++i) dst[i] = *(const bf16x8*)&(base)[offA[kk][(mh)*4 + i]]; } while (0)
#define RD_B(dst, base, kk) do { _Pragma("unroll")                            \
    for (int i = 0; i < 4; ++i) dst[i] = *(const bf16x8*)&(base)[offB[kk][i]]; } while (0)
#define MFMA16X(af, bfr, mh) do { _Pragma("unroll")                           \
    for (int i = 0; i < 4; ++i) { _Pragma("unroll")                           \
        for (int nt = 0; nt < 4; ++nt)                                        \
            acc[(mh)*4 + i][nt] = __builtin_amdgcn_mfma_f32_16x16x32_bf16(    \
                af[i], bfr[nt], acc[(mh)*4 + i][nt], 0, 0, 0); } } while (0)
#define VMC(n) asm volatile("s_waitcnt vmcnt(" #n ")" ::: "memory")
#define HBAR  __builtin_amdgcn_s_barrier()
#define LGKM(n) do { asm volatile("s_waitcnt lgkmcnt(" #n ")" ::: "memory");  \
                     __builtin_amdgcn_sched_barrier(0); } while (0)
#define SBAR  __builtin_amdgcn_sched_barrier(0)
#define PRIO1 __builtin_amdgcn_s_setprio(1)
#define PRIO0 __builtin_amdgcn_s_setprio(0)

    f32x4 acc[8][4] = {};
    bf16x8 afA[4], afB[4], bfrA[4], bfrB[4];
    const int mask = NTILES - 1;

    STA(0, 0, 0); STB(0, 0, 0); STA(0, 1, 0); STB(0, 1, 0);
    VMC(4); HBAR;
    RD_A(afA, As[0], 0, 0); RD_B(bfrA, Bs[0], 0);

    for (int t = 0; t < NTILES; ++t) {
        const int cur = t & 1, oth = cur ^ 1;
        const int ko = ((t + 1) & mask) * 64;
        const bf16_t* as  = As[cur];
        const bf16_t* bs  = Bs[cur];
        const bf16_t* asn = As[oth];
        const bf16_t* bsn = Bs[oth];
        // P1
        RD_A(afB, as, 0, 1); SBAR;
        STA(oth, 0, ko); SBAR;
        LGKM(4);
        PRIO1; MFMA16X(afA, bfrA, 0); PRIO0; SBAR;
        // P2
        VMC(2); HBAR;
        RD_A(afA, as, 1, 0); RD_B(bfrB, bs, 1); SBAR;
        STB(oth, 0, ko); SBAR;
        LGKM(8);
        PRIO1; MFMA16X(afB, bfrA, 1); PRIO0; SBAR;
        // P3
        RD_A(afB, as, 1, 1); SBAR;
        STA(oth, 1, ko); SBAR;
        LGKM(4);
        PRIO1; MFMA16X(afA, bfrB, 0); PRIO0; SBAR;
        // P4
        VMC(2); HBAR;
        RD_A(afA, asn, 0, 0); RD_B(bfrA, bsn, 0); SBAR;
        STB(oth, 1, ko); SBAR;
        LGKM(8);
        PRIO1; MFMA16X(afB, bfrB, 1); PRIO0; SBAR;
    }
#undef STA
#undef STB
#undef RD_A
#undef RD_B
#undef MFMA16X
#undef VMC
#undef HBAR
#undef LGKM
#undef SBAR
#undef PRIO1
#undef PRIO0

    if constexpr (EPI == 0) {
        // Plain epilogue: C/D layout row=(lane>>4)*4+reg, col=lane&15
#pragma unroll
        for (int mt = 0; mt < 8; ++mt) {
#pragma unroll
            for (int r = 0; r < 4; ++r) {
                const int row = m0 + wm * 128 + mt * 16 + ((lane >> 4) << 2) + r;
                const float bm = bias_m ? bias_m[row] : 0.0f;
#pragma unroll
                for (int nt = 0; nt < 4; ++nt) {
                    const int col = n0 + wn * 64 + nt * 16 + (lane & 15);
                    C[(size_t)row * ldc + col] = (bf16_t)(acc[mt][nt][r] + bm);
                }
            }
        }
    } else {
        // Fused epilogue, coalesced via double-banked LDS + one barrier/chunk.
        asm volatile("s_waitcnt vmcnt(0) lgkmcnt(0)" ::: "memory");
        __syncthreads();
        float* lsc0 = (float*)&As[0][0];     // 32 KiB = [32][256] f32
        float* lsc1 = (float*)&As[1][0];     // second bank
        const float alpha = alphap[0];
        const float onepb = 1.0f + betap[0];
        float mu = 0.f, rs = 0.f;
        if constexpr (EPI == 1) { mu = musig[bz]; rs = musig[16 + bz]; }
        const float* xb = (EPI == 1) ? xp + ((size_t)bz << 20) : nullptr;
        const bf16_t* xnb = (EPI == 2) ? xnp + ((size_t)bz << 20) : nullptr;
        float* ob = outp + ((size_t)bz << 20);
        const int lrow = wm * 16 + ((lane >> 4) << 2);
        const int lcol = wn * 64 + (lane & 15);
        const int gr = tid >> 4;             // 0..31 local row
        const int gc = (tid & 15) * 16;      // col base, 16 consecutive floats
#define SCAT(mt, bank) do { _Pragma("unroll")                                 \
    for (int r = 0; r < 4; ++r) { _Pragma("unroll")                           \
        for (int nt = 0; nt < 4; ++nt)                                        \
            (bank)[(lrow + r) * 256 + lcol + nt * 16] = acc[mt][nt][r]; } } while (0)
        SCAT(0, lsc0);
        __syncthreads();
#pragma unroll
        for (int mt = 0; mt < 8; ++mt) {
            float* bank  = (mt & 1) ? lsc1 : lsc0;
            float* nbank = (mt & 1) ? lsc0 : lsc1;
            const int grow = m0 + (gr >> 4) * 128 + mt * 16 + (gr & 15);
            const size_t idx = (size_t)grow * FF + n0 + gc;
            // hoisted global loads (independent of LDS)
            const bf16x8 vt0 = *(const bf16x8*)&A[(size_t)grow * lda + n0 + gc];
            const bf16x8 vt1 = *(const bf16x8*)&A[(size_t)grow * lda + n0 + gc + 8];
            bf16x8 xn0, xn1;
            float4 xv[4], wv[4], bv4[4];
            if constexpr (EPI == 2) {
                xn0 = *(const bf16x8*)&xnb[idx];
                xn1 = *(const bf16x8*)&xnb[idx + 8];
            } else {
#pragma unroll
                for (int j = 0; j < 4; ++j) {
                    xv[j]  = *(const float4*)&xb[idx + j * 4];
                    wv[j]  = *(const float4*)&lwp[idx + j * 4];
                    bv4[j] = *(const float4*)&lbp[idx + j * 4];
                }
            }
            if (mt < 7) {
                switch (mt + 1) {   // static index per rule #20 (unrolled loop)
                    case 1: SCAT(1, nbank); break;
                    case 2: SCAT(2, nbank); break;
                    case 3: SCAT(3, nbank); break;
                    case 4: SCAT(4, nbank); break;
                    case 5: SCAT(5, nbank); break;
                    case 6: SCAT(6, nbank); break;
                    case 7: SCAT(7, nbank); break;
                }
            }
#pragma unroll
            for (int j = 0; j < 4; ++j) {
                const float4 av = *(const float4*)&bank[gr * 256 + gc + j * 4];
                float4 o;
                if constexpr (EPI == 2) {
                    const int e = (j & 1) * 4;
                    const bf16x8& xs = (j < 2) ? xn0 : xn1;
                    const bf16x8& vs = (j < 2) ? vt0 : vt1;
                    o.x = (float)xs[e + 0] + alpha * av.x + onepb * (float)vs[e + 0];
                    o.y = (float)xs[e + 1] + alpha * av.y + onepb * (float)vs[e + 1];
                    o.z = (float)xs[e + 2] + alpha * av.z + onepb * (float)vs[e + 2];
                    o.w = (float)xs[e + 3] + alpha * av.w + onepb * (float)vs[e + 3];
                } else {
                    const int e = (j & 1) * 4;
                    const bf16x8& vs = (j < 2) ? vt0 : vt1;
                    o.x = (xv[j].x - mu) * rs * wv[j].x + bv4[j].x + alpha * av.x + onepb * (float)vs[e + 0];
                    o.y = (xv[j].y - mu) * rs * wv[j].y + bv4[j].y + alpha * av.y + onepb * (float)vs[e + 1];
                    o.z = (xv[j].z - mu) * rs * wv[j].z + bv4[j].z + alpha * av.z + onepb * (float)vs[e + 2];
                    o.w = (xv[j].w - mu) * rs * wv[j].w + bv4[j].w + alpha * av.w + onepb * (float)vs[e + 3];
                }
                *(float4*)&ob[idx + j * 4] = o;
            }
            __syncthreads();
        }
#undef SCAT
    }
}

__global__ __launch_bounds__(512, 2) void g1_mm(
        const bf16_t* A, long long sA, int lda, const bf16_t* B, long long sB, int ldb,
        bf16_t* C, long long sC, int ldc, int NT, const float* bias_m) {
    gemm_impl<0>(A, sA, lda, B, sB, ldb, C, sC, ldc, NT, bias_m,
                 nullptr, nullptr, nullptr, nullptr, nullptr, nullptr, nullptr, nullptr);
}

__global__ __launch_bounds__(512, 2) void g2_mm_full(
        const bf16_t* A, long long sA, int lda, const bf16_t* B, long long sB, int ldb,
        int NT, const float* xp, const float* lwp, const float* lbp,
        const float* musig, const float* alphap, const float* betap, float* outp) {
    gemm_impl<1>(A, sA, lda, B, sB, ldb, nullptr, 0, FF, NT, nullptr,
                 xp, lwp, lbp, nullptr, musig, alphap, betap, outp);
}

__global__ __launch_bounds__(512, 2) void g2_mm_lite(
        const bf16_t* A, long long sA, int lda, const bf16_t* B, long long sB, int ldb,
        int NT, const bf16_t* xnp,
        const float* musig, const float* alphap, const float* betap, float* outp) {
    gemm_impl<2>(A, sA, lda, B, sB, ldb, nullptr, 0, FF, NT, nullptr,
                 nullptr, nullptr, nullptr, xnp, musig, alphap, betap, outp);
}

extern "C" void kernel_launch(void* const* d_in, const int* in_sizes, int n_in,
                              void* d_out, int out_size, void* d_ws, size_t ws_size,
                              hipStream_t stream) {
    const float* x   = (const float*)d_in[0];
    const float* Wq  = (const float*)d_in[1];
    const float* bq  = (const float*)d_in[2];
    const float* Wk  = (const float*)d_in[3];
    const float* bk  = (const float*)d_in[4];
    const float* Wv  = (const float*)d_in[5];
    const float* bv  = (const float*)d_in[6];
    const float* lw  = (const float*)d_in[7];
    const float* lb  = (const float*)d_in[8];
    const float* alp = (const float*)d_in[9];
    const float* bet = (const float*)d_in[10];
    float* out = (float*)d_out;

    char* ws = (char*)d_ws;
    float*  musig = (float*)(ws + 128);         // 32 f32: mu[16], rsig[16]
    float*  Qo    = (float*)(ws + 256);         // 16*512*4 f32 = 128 KiB
    float*  Ko    = (float*)(ws + 256 + 131072);
    bf16_t* Wvb   = (bf16_t*)(ws + 262400);     // 2048*2048 bf16 = 8 MiB
    bf16_t* Asm   = (bf16_t*)(ws + 8651008);    // 16*512*512 bf16 = 8 MiB
    float*  partials = (float*)(ws + 8651008);  // 2048 f32 — dead before Asm written
    bf16_t* Vt    = (bf16_t*)(ws + 17039616);   // 16*2048*512 bf16 = 32 MiB
    bf16_t* Y     = (bf16_t*)(ws + 50594048);   // 16*512*2048 bf16 = 32 MiB
    bf16_t* Xn    = (bf16_t*)(ws + 84148480);   // 16*2048*512 bf16 = 32 MiB (optional)
    const bool lite = ws_size >= (size_t)117702912;

    stats_kernel<<<dim3(64, 16), 256, 0, stream>>>(x, partials);
    finalize_stats<<<1, 256, 0, stream>>>(partials, musig);
    cast_wv<<<4096, 256, 0, stream>>>(Wv, Wvb);
    ynorm_kernel<<<dim3(16, 64, 16), 256, 0, stream>>>(x, lw, lb, musig, Y,
                                                       lite ? Xn : (bf16_t*)nullptr);
    qk_kernel<<<2048, 256, 0, stream>>>(Y, Wq, bq, Wk, bk, Qo, Ko);
    softmax_kernel<<<2048, 256, 0, stream>>>(Qo, Ko, Asm);
    // Vt[b,t,f] = sum_s Wv[t,s]*Y[b,f,s] + bv[t]   (M=2048,N=512,K=2048 -> 32 tiles)
    g1_mm<<<256, 512, 0, stream>>>(Wvb, 0, SS, Y, 1 << 20, SS, Vt, 1 << 20, FF, 32, bv);
    // out[b,t,f] = x_norm + alpha*(Vt.Asm^T) + (1+beta)*Vt  (M=2048,N=512,K=512)
    if (lite) {
        g2_mm_lite<<<256, 512, 0, stream>>>(Vt, 1 << 20, FF, Asm, FF * FF, FF, 8,
                                            Xn, musig, alp, bet, out);
    } else {
        g2_mm_full<<<256, 512, 0, stream>>>(Vt, 1 << 20, FF, Asm, FF * FF, FF, 8,
                                            x, lw, lb, musig, alp, bet, out);
    }
}

// Round 11
// 179.992 us; speedup vs baseline: 1.1393x; 1.0102x over previous
//
#include <hip/hip_runtime.h>
#include <hip/hip_bf16.h>

// Problem constants
#define NB 16        // batches
#define SS 2048      // S
#define FF 512       // F

typedef __bf16 bf16_t;
typedef __bf16 bf16x8 __attribute__((ext_vector_type(8)));
typedef __bf16 bf16x4 __attribute__((ext_vector_type(4)));
typedef float  f32x4  __attribute__((ext_vector_type(4)));

// ---------------------------------------------------------------- LN stats
__global__ __launch_bounds__(256) void stats_kernel(const float* __restrict__ x,
                                                    float* __restrict__ partials) {
    const int b = blockIdx.y;
    const float* xb = x + ((size_t)b << 20) + (size_t)blockIdx.x * 16384;
    float s = 0.0f, ss = 0.0f;
#pragma unroll
    for (int i = 0; i < 16; ++i) {
        const float4 v = *(const float4*)&xb[(threadIdx.x + i * 256) * 4];
        s  += v.x + v.y + v.z + v.w;
        ss += v.x * v.x + v.y * v.y + v.z * v.z + v.w * v.w;
    }
#pragma unroll
    for (int off = 32; off > 0; off >>= 1) {
        s  += __shfl_down(s, off);
        ss += __shfl_down(ss, off);
    }
    __shared__ float ps[4], pss[4];
    const int w = threadIdx.x >> 6, lane = threadIdx.x & 63;
    if (lane == 0) { ps[w] = s; pss[w] = ss; }
    __syncthreads();
    if (threadIdx.x == 0) {
        partials[b * 64 + blockIdx.x]        = ps[0] + ps[1] + ps[2] + ps[3];
        partials[1024 + b * 64 + blockIdx.x] = pss[0] + pss[1] + pss[2] + pss[3];
    }
}

__global__ __launch_bounds__(256) void finalize_stats(const float* __restrict__ partials,
                                                      float* __restrict__ musig) {
    const int tid = threadIdx.x;          // 0..255
    const int b = tid >> 4, i = tid & 15;
    float s = 0.f, ss = 0.f;
#pragma unroll
    for (int j = 0; j < 4; ++j) {
        s  += partials[b * 64 + i * 4 + j];
        ss += partials[1024 + b * 64 + i * 4 + j];
    }
#pragma unroll
    for (int off = 8; off > 0; off >>= 1) {
        s  += __shfl_xor(s, off);
        ss += __shfl_xor(ss, off);
    }
    if (i == 0) {
        const float inv_n = 1.0f / 1048576.0f;
        const float mu  = s * inv_n;
        const float var = ss * inv_n - mu * mu;
        musig[b]      = mu;
        musig[16 + b] = rsqrtf(var + 1e-5f);
    }
}

// ------------------------------------------------- x_norm -> Y bf16 [b][f][s]
// Also (optionally) writes Xn = x_norm bf16 in [b][s][f] for the fused epilogue.
__global__ __launch_bounds__(256) void ynorm_kernel(const float* __restrict__ x,
                                                    const float* __restrict__ lw,
                                                    const float* __restrict__ lb,
                                                    const float* __restrict__ musig,
                                                    bf16_t* __restrict__ Y,
                                                    bf16_t* __restrict__ Xn) {
    __shared__ bf16_t t[32][36];         // [s][f], +4 pad
    const int b = blockIdx.z;
    const int f0 = blockIdx.x * 32, s0 = blockIdx.y * 32;
    const float mu = musig[b], rs = musig[16 + b];
    const int tid = threadIdx.x;
    {
        const int s_loc = tid >> 3, c4 = (tid & 7) * 4;
        const size_t idx = (size_t)(s0 + s_loc) * FF + f0 + c4;
        const float4 xv = *(const float4*)&x[((size_t)b << 20) + idx];
        const float4 wv = *(const float4*)&lw[idx];
        const float4 bv = *(const float4*)&lb[idx];
        bf16x4 o;
        o[0] = (bf16_t)((xv.x - mu) * rs * wv.x + bv.x);
        o[1] = (bf16_t)((xv.y - mu) * rs * wv.y + bv.y);
        o[2] = (bf16_t)((xv.z - mu) * rs * wv.z + bv.z);
        o[3] = (bf16_t)((xv.w - mu) * rs * wv.w + bv.w);
        t[s_loc][c4 + 0] = o[0];
        t[s_loc][c4 + 1] = o[1];
        t[s_loc][c4 + 2] = o[2];
        t[s_loc][c4 + 3] = o[3];
        if (Xn) *(bf16x4*)&Xn[((size_t)b << 20) + idx] = o;
    }
    __syncthreads();
    {
        const int f_loc = tid >> 3, s4 = (tid & 7) * 4;
        bf16x4 o;
        o[0] = t[s4 + 0][f_loc];
        o[1] = t[s4 + 1][f_loc];
        o[2] = t[s4 + 2][f_loc];
        o[3] = t[s4 + 3][f_loc];
        *(bf16x4*)&Y[((size_t)b << 20) + (size_t)(f0 + f_loc) * SS + s0 + s4] = o;
    }
}

// ---------------------------------------------------------------- Wv -> bf16
__global__ __launch_bounds__(256) void cast_wv(const float* __restrict__ Wv,
                                               bf16_t* __restrict__ Wvb) {
    const size_t i = ((size_t)blockIdx.x * 256 + threadIdx.x) * 4;
    const float4 v = *(const float4*)&Wv[i];
    bf16x4 o;
    o[0] = (bf16_t)v.x; o[1] = (bf16_t)v.y; o[2] = (bf16_t)v.z; o[3] = (bf16_t)v.w;
    *(bf16x4*)&Wvb[i] = o;
}

// ------------------------------- Q,K: 4 rows/wave, weight loads amortized x4
__global__ __launch_bounds__(256) void qk_kernel(const bf16_t* __restrict__ Y,
                                                 const float* __restrict__ Wq,
                                                 const float* __restrict__ bq,
                                                 const float* __restrict__ Wk,
                                                 const float* __restrict__ bk,
                                                 float* __restrict__ Qo,
                                                 float* __restrict__ Ko) {
    const int w = threadIdx.x >> 6, lane = threadIdx.x & 63;
    const int row0 = blockIdx.x * 16 + w * 4;        // b*512 + f, 4 rows per wave
    const bf16_t* y0 = Y + (size_t)row0 * SS;
    float qa[4][4] = {}, ka[4][4] = {};              // [row][r]
#pragma unroll
    for (int c = 0; c < 4; ++c) {
        const int s = c * 512 + lane * 8;
        float yf[4][8];
#pragma unroll
        for (int rr = 0; rr < 4; ++rr) {
            const bf16x8 yv = *(const bf16x8*)&y0[(size_t)rr * SS + s];
#pragma unroll
            for (int j = 0; j < 8; ++j) yf[rr][j] = (float)yv[j];
        }
#pragma unroll
        for (int r = 0; r < 4; ++r) {
            const float4 a0 = *(const float4*)&Wq[r * SS + s];
            const float4 a1 = *(const float4*)&Wq[r * SS + s + 4];
            const float4 c0 = *(const float4*)&Wk[r * SS + s];
            const float4 c1 = *(const float4*)&Wk[r * SS + s + 4];
#pragma unroll
            for (int rr = 0; rr < 4; ++rr) {
                qa[rr][r] += yf[rr][0]*a0.x + yf[rr][1]*a0.y + yf[rr][2]*a0.z + yf[rr][3]*a0.w
                           + yf[rr][4]*a1.x + yf[rr][5]*a1.y + yf[rr][6]*a1.z + yf[rr][7]*a1.w;
                ka[rr][r] += yf[rr][0]*c0.x + yf[rr][1]*c0.y + yf[rr][2]*c0.z + yf[rr][3]*c0.w
                           + yf[rr][4]*c1.x + yf[rr][5]*c1.y + yf[rr][6]*c1.z + yf[rr][7]*c1.w;
            }
        }
    }
#pragma unroll
    for (int off = 32; off > 0; off >>= 1) {
#pragma unroll
        for (int rr = 0; rr < 4; ++rr)
#pragma unroll
            for (int r = 0; r < 4; ++r) {
                qa[rr][r] += __shfl_down(qa[rr][r], off);
                ka[rr][r] += __shfl_down(ka[rr][r], off);
            }
    }
    if (lane == 0) {
#pragma unroll
        for (int rr = 0; rr < 4; ++rr)
#pragma unroll
            for (int r = 0; r < 4; ++r) {
                Qo[(size_t)(row0 + rr) * 4 + r] = qa[rr][r] + bq[r];
                Ko[(size_t)(row0 + rr) * 4 + r] = ka[rr][r] + bk[r];
            }
    }
}

// ----------------------------------- A = softmax(Q K^T / sqrt(4)), bf16 output
__global__ __launch_bounds__(256) void softmax_kernel(const float* __restrict__ Qo,
                                                      const float* __restrict__ Ko,
                                                      bf16_t* __restrict__ Aout) {
    const int w = threadIdx.x >> 6, lane = threadIdx.x & 63;
    const int row = blockIdx.x * 4 + w;              // b*512 + f
    const int b = row >> 9;
    const float4 q = *(const float4*)&Qo[(size_t)row * 4];
    const float* kb = Ko + (size_t)b * FF * 4;
    float sc[8];
#pragma unroll
    for (int j = 0; j < 8; ++j) {
        const float4 kv = *(const float4*)&kb[(lane * 8 + j) * 4];
        sc[j] = (q.x*kv.x + q.y*kv.y + q.z*kv.z + q.w*kv.w) * 0.5f;
    }
    float mx = sc[0];
#pragma unroll
    for (int j = 1; j < 8; ++j) mx = fmaxf(mx, sc[j]);
#pragma unroll
    for (int off = 32; off > 0; off >>= 1) mx = fmaxf(mx, __shfl_xor(mx, off));
    float sum = 0.f;
#pragma unroll
    for (int j = 0; j < 8; ++j) { sc[j] = __expf(sc[j] - mx); sum += sc[j]; }
#pragma unroll
    for (int off = 32; off > 0; off >>= 1) sum += __shfl_xor(sum, off);
    const float inv = 1.0f / sum;
    bf16x8 o;
#pragma unroll
    for (int j = 0; j < 8; ++j) o[j] = (bf16_t)(sc[j] * inv);
    *(bf16x8*)&Aout[(size_t)row * FF + lane * 8] = o;
}

// --------------------------------------------------------------- NT bf16 GEMM
// r9 read-ahead pipeline + r11 stage-reorder: ALL 8 next-tile stage loads
// issued at P1; waits renumbered vmcnt(8)@P2 (h1-of-cur, issued a full tile
// ago -> no stall) and vmcnt(4)@P4 (h0-of-next, issued 3 phases ago). Two
// barriers/tile. Counted lgkm(4/8/4/8) forces exactly the consumed cluster.
// EPI: 0 = plain bf16 C-write; 1 = fused (x/lw/lb fp32); 2 = fused (Xn bf16).
template<int EPI>
__device__ __forceinline__ void gemm_impl(
        const bf16_t* __restrict__ Abase, long long strideA, int lda,
        const bf16_t* __restrict__ Bbase, long long strideB, int ldb,
        bf16_t* __restrict__ Cbase, long long strideC, int ldc,
        int NTILES, const float* __restrict__ bias_m,
        const float* __restrict__ xp, const float* __restrict__ lwp,
        const float* __restrict__ lbp, const bf16_t* __restrict__ xnp,
        const float* __restrict__ musig,
        const float* __restrict__ alphap, const float* __restrict__ betap,
        float* __restrict__ outp) {
    __shared__ __align__(16) bf16_t As[2][16384];   // [buf][kk*8192 + row*32 + swz]
    __shared__ __align__(16) bf16_t Bs[2][16384];   // total 128 KiB
    const int tid = threadIdx.x;
    const int w = tid >> 6, lane = tid & 63;

    // XCD-bijective swizzle (nwg = 256, 256 % 8 == 0)
    const int nchunk = gridDim.x >> 3;                               // 32
    const int wgid = (blockIdx.x & 7) * nchunk + (blockIdx.x >> 3);
    const int bz = wgid >> 4;            // batch
    const int rem = wgid & 15;
    const int m0 = (rem & 7) * 256, n0 = (rem >> 3) * 256;

    const bf16_t* A = Abase + (size_t)bz * (size_t)strideA;
    const bf16_t* B = Bbase + (size_t)bz * (size_t)strideB;
    bf16_t* C = Cbase + (size_t)bz * (size_t)strideC;
    const int wm = w >> 2, wn = w & 3;   // wave tile rows wm*128.., cols wn*64..

    const int rr0 = (w * 2 + 0) * 16 + (lane >> 2);
    const int rr1 = (w * 2 + 1) * 16 + (lane >> 2);
    const int sw0 = ((lane & 3) ^ ((rr0 >> 1) & 3)) * 8;
    const int sw1 = ((lane & 3) ^ ((rr1 >> 1) & 3)) * 8;
    const bf16_t* gA0 = A + (size_t)(m0 + rr0) * lda + sw0;
    const bf16_t* gA1 = A + (size_t)(m0 + rr1) * lda + sw1;
    const bf16_t* gB0 = B + (size_t)(n0 + rr0) * ldb + sw0;
    const bf16_t* gB1 = B + (size_t)(n0 + rr1) * ldb + sw1;
    const int d0 = (w * 2 + 0) * 512;
    const int d1 = (w * 2 + 1) * 512;

#define STA(bi, h, ko) do {                                                          \
    __builtin_amdgcn_global_load_lds(                                                \
        (const __attribute__((address_space(1))) unsigned int*)(gA0 + (ko) + (h)*32),\
        (__attribute__((address_space(3))) unsigned int*)&As[bi][(h)*8192 + d0], 16, 0, 0); \
    __builtin_amdgcn_global_load_lds(                                                \
        (const __attribute__((address_space(1))) unsigned int*)(gA1 + (ko) + (h)*32),\
        (__attribute__((address_space(3))) unsigned int*)&As[bi][(h)*8192 + d1], 16, 0, 0); \
} while (0)
#define STB(bi, h, ko) do {                                                          \
    __builtin_amdgcn_global_load_lds(                                                \
        (const __attribute__((address_space(1))) unsigned int*)(gB0 + (ko) + (h)*32),\
        (__attribute__((address_space(3))) unsigned int*)&Bs[bi][(h)*8192 + d0], 16, 0, 0); \
    __builtin_amdgcn_global_load_lds(                                                \
        (const __attribute__((address_space(1))) unsigned int*)(gB1 + (ko) + (h)*32),\
        (__attribute__((address_space(3))) unsigned int*)&Bs[bi][(h)*8192 + d1], 16, 0, 0); \
} while (0)

    const int cs = lane >> 4;
    int offA[2][8], offB[2][4];
#pragma unroll
    for (int kk = 0; kk < 2; ++kk) {
#pragma unroll
        for (int mt = 0; mt < 8; ++mt) {
            const int r = wm * 128 + mt * 16 + (lane & 15);
            offA[kk][mt] = kk * 8192 + r * 32 + ((cs ^ ((r >> 1) & 3)) << 3);
        }
#pragma unroll
        for (int nt = 0; nt < 4; ++nt) {
            const int r = wn * 64 + nt * 16 + (lane & 15);
            offB[kk][nt] = kk * 8192 + r * 32 + ((cs ^ ((r >> 1) & 3)) << 3);
        }
    }

#define RD_A(dst, base, kk, mh) do { _Pragma("unroll")                        \
    for (int i = 0; i < 4; ++i) dst[i] = *(const bf16x8*)&(base)[offA[kk][(mh)*4 + i]]; } while (0)
#define RD_B(dst, base, kk) do { _Pragma("unroll")                            \
    for (int i = 0; i < 4; ++i) dst[i] = *(const bf16x8*)&(base)[offB[kk][i]]; } while (0)
#define MFMA16X(af, bfr, mh) do { _Pragma("unroll")                           \
    for (int i = 0; i < 4; ++i) { _Pragma("unroll")                           \
        for (int nt = 0; nt < 4; ++nt)                                        \
            acc[(mh)*4 + i][nt] = __builtin_amdgcn_mfma_f32_16x16x32_bf16(    \
                af[i], bfr[nt], acc[(mh)*4 + i][nt], 0, 0, 0); } } while (0)
#define VMC(n) asm volatile("s_waitcnt vmcnt(" #n ")" ::: "memory")
#define HBAR  __builtin_amdgcn_s_barrier()
#define LGKM(n) do { asm volatile("s_waitcnt lgkmcnt(" #n ")" ::: "memory");  \
                     __builtin_amdgcn_sched_barrier(0); } while (0)
#define SBAR  __builtin_amdgcn_sched_barrier(0)
#define PRIO1 __builtin_amdgcn_s_setprio(1)
#define PRIO0 __builtin_amdgcn_s_setprio(0)

    f32x4 acc[8][4] = {};
    bf16x8 afA[4], afB[4], bfrA[4], bfrB[4];
    const int mask = NTILES - 1;

    // prologue: tile 0 into buf 0; force h0 landed; read C1
    STA(0, 0, 0); STB(0, 0, 0); STA(0, 1, 0); STB(0, 1, 0);
    VMC(4); HBAR;
    RD_A(afA, As[0], 0, 0); RD_B(bfrA, Bs[0], 0);

    for (int t = 0; t < NTILES; ++t) {
        const int cur = t & 1, oth = cur ^ 1;
        const int ko = ((t + 1) & mask) * 64;
        const bf16_t* as  = As[cur];
        const bf16_t* bs  = Bs[cur];
        const bf16_t* asn = As[oth];
        const bf16_t* bsn = Bs[oth];
        // P1: read C2; issue ALL 8 stages for t+1; consume C1
        RD_A(afB, as, 0, 1); SBAR;
        STA(oth, 0, ko); STB(oth, 0, ko); STA(oth, 1, ko); STB(oth, 1, ko); SBAR;
        LGKM(4);
        PRIO1; MFMA16X(afA, bfrA, 0); PRIO0; SBAR;
        // P2: h1-of-cur landed (issued a full tile ago): VMC(8)+HBAR; read C3
        VMC(8); HBAR;
        RD_A(afA, as, 1, 0); RD_B(bfrB, bs, 1); SBAR;
        LGKM(8);
        PRIO1; MFMA16X(afB, bfrA, 1); PRIO0; SBAR;
        // P3: read C4; consume C3
        RD_A(afB, as, 1, 1); SBAR;
        LGKM(4);
        PRIO1; MFMA16X(afA, bfrB, 0); PRIO0; SBAR;
        // P4: h0-of-next landed (issued 3 phases ago): VMC(4)+HBAR; read next C1
        VMC(4); HBAR;
        RD_A(afA, asn, 0, 0); RD_B(bfrA, bsn, 0); SBAR;
        LGKM(8);
        PRIO1; MFMA16X(afB, bfrB, 1); PRIO0; SBAR;
    }
#undef STA
#undef STB
#undef RD_A
#undef RD_B
#undef MFMA16X
#undef VMC
#undef HBAR
#undef LGKM
#undef SBAR
#undef PRIO1
#undef PRIO0

    if constexpr (EPI == 0) {
        // Plain epilogue: C/D layout row=(lane>>4)*4+reg, col=lane&15
#pragma unroll
        for (int mt = 0; mt < 8; ++mt) {
#pragma unroll
            for (int r = 0; r < 4; ++r) {
                const int row = m0 + wm * 128 + mt * 16 + ((lane >> 4) << 2) + r;
                const float bm = bias_m ? bias_m[row] : 0.0f;
#pragma unroll
                for (int nt = 0; nt < 4; ++nt) {
                    const int col = n0 + wn * 64 + nt * 16 + (lane & 15);
                    C[(size_t)row * ldc + col] = (bf16_t)(acc[mt][nt][r] + bm);
                }
            }
        }
    } else {
        // Fused epilogue, coalesced via double-banked LDS + one barrier/chunk.
        asm volatile("s_waitcnt vmcnt(0) lgkmcnt(0)" ::: "memory");
        __syncthreads();
        float* lsc0 = (float*)&As[0][0];     // 32 KiB = [32][256] f32
        float* lsc1 = (float*)&As[1][0];     // second bank
        const float alpha = alphap[0];
        const float onepb = 1.0f + betap[0];
        float mu = 0.f, rs = 0.f;
        if constexpr (EPI == 1) { mu = musig[bz]; rs = musig[16 + bz]; }
        const float* xb = (EPI == 1) ? xp + ((size_t)bz << 20) : nullptr;
        const bf16_t* xnb = (EPI == 2) ? xnp + ((size_t)bz << 20) : nullptr;
        float* ob = outp + ((size_t)bz << 20);
        const int lrow = wm * 16 + ((lane >> 4) << 2);
        const int lcol = wn * 64 + (lane & 15);
        const int gr = tid >> 4;             // 0..31 local row
        const int gc = (tid & 15) * 16;      // col base, 16 consecutive floats
#define SCAT(mt, bank) do { _Pragma("unroll")                                 \
    for (int r = 0; r < 4; ++r) { _Pragma("unroll")                           \
        for (int nt = 0; nt < 4; ++nt)                                        \
            (bank)[(lrow + r) * 256 + lcol + nt * 16] = acc[mt][nt][r]; } } while (0)
        SCAT(0, lsc0);
        __syncthreads();
#pragma unroll
        for (int mt = 0; mt < 8; ++mt) {
            float* bank  = (mt & 1) ? lsc1 : lsc0;
            float* nbank = (mt & 1) ? lsc0 : lsc1;
            const int grow = m0 + (gr >> 4) * 128 + mt * 16 + (gr & 15);
            const size_t idx = (size_t)grow * FF + n0 + gc;
            // hoisted global loads (independent of LDS)
            const bf16x8 vt0 = *(const bf16x8*)&A[(size_t)grow * lda + n0 + gc];
            const bf16x8 vt1 = *(const bf16x8*)&A[(size_t)grow * lda + n0 + gc + 8];
            bf16x8 xn0, xn1;
            float4 xv[4], wv[4], bv4[4];
            if constexpr (EPI == 2) {
                xn0 = *(const bf16x8*)&xnb[idx];
                xn1 = *(const bf16x8*)&xnb[idx + 8];
            } else {
#pragma unroll
                for (int j = 0; j < 4; ++j) {
                    xv[j]  = *(const float4*)&xb[idx + j * 4];
                    wv[j]  = *(const float4*)&lwp[idx + j * 4];
                    bv4[j] = *(const float4*)&lbp[idx + j * 4];
                }
            }
            if (mt < 7) {
                switch (mt + 1) {   // static index per rule #20 (unrolled loop)
                    case 1: SCAT(1, nbank); break;
                    case 2: SCAT(2, nbank); break;
                    case 3: SCAT(3, nbank); break;
                    case 4: SCAT(4, nbank); break;
                    case 5: SCAT(5, nbank); break;
                    case 6: SCAT(6, nbank); break;
                    case 7: SCAT(7, nbank); break;
                }
            }
#pragma unroll
            for (int j = 0; j < 4; ++j) {
                const float4 av = *(const float4*)&bank[gr * 256 + gc + j * 4];
                float4 o;
                if constexpr (EPI == 2) {
                    const int e = (j & 1) * 4;
                    const bf16x8& xs = (j < 2) ? xn0 : xn1;
                    const bf16x8& vs = (j < 2) ? vt0 : vt1;
                    o.x = (float)xs[e + 0] + alpha * av.x + onepb * (float)vs[e + 0];
                    o.y = (float)xs[e + 1] + alpha * av.y + onepb * (float)vs[e + 1];
                    o.z = (float)xs[e + 2] + alpha * av.z + onepb * (float)vs[e + 2];
                    o.w = (float)xs[e + 3] + alpha * av.w + onepb * (float)vs[e + 3];
                } else {
                    const int e = (j & 1) * 4;
                    const bf16x8& vs = (j < 2) ? vt0 : vt1;
                    o.x = (xv[j].x - mu) * rs * wv[j].x + bv4[j].x + alpha * av.x + onepb * (float)vs[e + 0];
                    o.y = (xv[j].y - mu) * rs * wv[j].y + bv4[j].y + alpha * av.y + onepb * (float)vs[e + 1];
                    o.z = (xv[j].z - mu) * rs * wv[j].z + bv4[j].z + alpha * av.z + onepb * (float)vs[e + 2];
                    o.w = (xv[j].w - mu) * rs * wv[j].w + bv4[j].w + alpha * av.w + onepb * (float)vs[e + 3];
                }
                *(float4*)&ob[idx + j * 4] = o;
            }
            __syncthreads();
        }
#undef SCAT
    }
}

__global__ __launch_bounds__(512, 2) void g1_mm(
        const bf16_t* A, long long sA, int lda, const bf16_t* B, long long sB, int ldb,
        bf16_t* C, long long sC, int ldc, int NT, const float* bias_m) {
    gemm_impl<0>(A, sA, lda, B, sB, ldb, C, sC, ldc, NT, bias_m,
                 nullptr, nullptr, nullptr, nullptr, nullptr, nullptr, nullptr, nullptr);
}

__global__ __launch_bounds__(512, 2) void g2_mm_full(
        const bf16_t* A, long long sA, int lda, const bf16_t* B, long long sB, int ldb,
        int NT, const float* xp, const float* lwp, const float* lbp,
        const float* musig, const float* alphap, const float* betap, float* outp) {
    gemm_impl<1>(A, sA, lda, B, sB, ldb, nullptr, 0, FF, NT, nullptr,
                 xp, lwp, lbp, nullptr, musig, alphap, betap, outp);
}

__global__ __launch_bounds__(512, 2) void g2_mm_lite(
        const bf16_t* A, long long sA, int lda, const bf16_t* B, long long sB, int ldb,
        int NT, const bf16_t* xnp,
        const float* musig, const float* alphap, const float* betap, float* outp) {
    gemm_impl<2>(A, sA, lda, B, sB, ldb, nullptr, 0, FF, NT, nullptr,
                 nullptr, nullptr, nullptr, xnp, musig, alphap, betap, outp);
}

extern "C" void kernel_launch(void* const* d_in, const int* in_sizes, int n_in,
                              void* d_out, int out_size, void* d_ws, size_t ws_size,
                              hipStream_t stream) {
    const float* x   = (const float*)d_in[0];
    const float* Wq  = (const float*)d_in[1];
    const float* bq  = (const float*)d_in[2];
    const float* Wk  = (const float*)d_in[3];
    const float* bk  = (const float*)d_in[4];
    const float* Wv  = (const float*)d_in[5];
    const float* bv  = (const float*)d_in[6];
    const float* lw  = (const float*)d_in[7];
    const float* lb  = (const float*)d_in[8];
    const float* alp = (const float*)d_in[9];
    const float* bet = (const float*)d_in[10];
    float* out = (float*)d_out;

    char* ws = (char*)d_ws;
    float*  musig = (float*)(ws + 128);         // 32 f32: mu[16], rsig[16]
    float*  Qo    = (float*)(ws + 256);         // 16*512*4 f32 = 128 KiB
    float*  Ko    = (float*)(ws + 256 + 131072);
    bf16_t* Wvb   = (bf16_t*)(ws + 262400);     // 2048*2048 bf16 = 8 MiB
    bf16_t* Asm   = (bf16_t*)(ws + 8651008);    // 16*512*512 bf16 = 8 MiB
    float*  partials = (float*)(ws + 8651008);  // 2048 f32 — dead before Asm written
    bf16_t* Vt    = (bf16_t*)(ws + 17039616);   // 16*2048*512 bf16 = 32 MiB
    bf16_t* Y     = (bf16_t*)(ws + 50594048);   // 16*512*2048 bf16 = 32 MiB
    bf16_t* Xn    = (bf16_t*)(ws + 84148480);   // 16*2048*512 bf16 = 32 MiB (optional)
    const bool lite = ws_size >= (size_t)117702912;

    stats_kernel<<<dim3(64, 16), 256, 0, stream>>>(x, partials);
    finalize_stats<<<1, 256, 0, stream>>>(partials, musig);
    cast_wv<<<4096, 256, 0, stream>>>(Wv, Wvb);
    ynorm_kernel<<<dim3(16, 64, 16), 256, 0, stream>>>(x, lw, lb, musig, Y,
                                                       lite ? Xn : (bf16_t*)nullptr);
    qk_kernel<<<512, 256, 0, stream>>>(Y, Wq, bq, Wk, bk, Qo, Ko);
    softmax_kernel<<<2048, 256, 0, stream>>>(Qo, Ko, Asm);
    // Vt[b,t,f] = sum_s Wv[t,s]*Y[b,f,s] + bv[t]   (M=2048,N=512,K=2048 -> 32 tiles)
    g1_mm<<<256, 512, 0, stream>>>(Wvb, 0, SS, Y, 1 << 20, SS, Vt, 1 << 20, FF, 32, bv);
    // out[b,t,f] = x_norm + alpha*(Vt.Asm^T) + (1+beta)*Vt  (M=2048,N=512,K=512)
    if (lite) {
        g2_mm_lite<<<256, 512, 0, stream>>>(Vt, 1 << 20, FF, Asm, FF * FF, FF, 8,
                                            Xn, musig, alp, bet, out);
    } else {
        g2_mm_full<<<256, 512, 0, stream>>>(Vt, 1 << 20, FF, Asm, FF * FF, FF, 8,
                                            x, lw, lb, musig, alp, bet, out);
    }
}

// Round 12
// 174.139 us; speedup vs baseline: 1.1776x; 1.0336x over previous
//
#include <hip/hip_runtime.h>
#include <hip/hip_bf16.h>

// Problem constants
#define NB 16        // batches
#define SS 2048      // S
#define FF 512       // F

typedef __bf16 bf16_t;
typedef __bf16 bf16x8 __attribute__((ext_vector_type(8)));
typedef __bf16 bf16x4 __attribute__((ext_vector_type(4)));
typedef float  f32x4  __attribute__((ext_vector_type(4)));

// ---------------------------------------------------------------- LN stats
__global__ __launch_bounds__(256) void stats_kernel(const float* __restrict__ x,
                                                    float* __restrict__ partials) {
    const int b = blockIdx.y;
    const float* xb = x + ((size_t)b << 20) + (size_t)blockIdx.x * 16384;
    float s = 0.0f, ss = 0.0f;
#pragma unroll
    for (int i = 0; i < 16; ++i) {
        const float4 v = *(const float4*)&xb[(threadIdx.x + i * 256) * 4];
        s  += v.x + v.y + v.z + v.w;
        ss += v.x * v.x + v.y * v.y + v.z * v.z + v.w * v.w;
    }
#pragma unroll
    for (int off = 32; off > 0; off >>= 1) {
        s  += __shfl_down(s, off);
        ss += __shfl_down(ss, off);
    }
    __shared__ float ps[4], pss[4];
    const int w = threadIdx.x >> 6, lane = threadIdx.x & 63;
    if (lane == 0) { ps[w] = s; pss[w] = ss; }
    __syncthreads();
    if (threadIdx.x == 0) {
        partials[b * 64 + blockIdx.x]        = ps[0] + ps[1] + ps[2] + ps[3];
        partials[1024 + b * 64 + blockIdx.x] = pss[0] + pss[1] + pss[2] + pss[3];
    }
}

__global__ __launch_bounds__(256) void finalize_stats(const float* __restrict__ partials,
                                                      float* __restrict__ musig) {
    const int tid = threadIdx.x;          // 0..255
    const int b = tid >> 4, i = tid & 15;
    float s = 0.f, ss = 0.f;
#pragma unroll
    for (int j = 0; j < 4; ++j) {
        s  += partials[b * 64 + i * 4 + j];
        ss += partials[1024 + b * 64 + i * 4 + j];
    }
#pragma unroll
    for (int off = 8; off > 0; off >>= 1) {
        s  += __shfl_xor(s, off);
        ss += __shfl_xor(ss, off);
    }
    if (i == 0) {
        const float inv_n = 1.0f / 1048576.0f;
        const float mu  = s * inv_n;
        const float var = ss * inv_n - mu * mu;
        musig[b]      = mu;
        musig[16 + b] = rsqrtf(var + 1e-5f);
    }
}

// ------------------------------------------------- x_norm -> Y bf16 [b][f][s]
// Also (optionally) writes Xn = x_norm bf16 in [b][s][f] for the fused epilogue.
__global__ __launch_bounds__(256) void ynorm_kernel(const float* __restrict__ x,
                                                    const float* __restrict__ lw,
                                                    const float* __restrict__ lb,
                                                    const float* __restrict__ musig,
                                                    bf16_t* __restrict__ Y,
                                                    bf16_t* __restrict__ Xn) {
    __shared__ bf16_t t[32][36];         // [s][f], +4 pad
    const int b = blockIdx.z;
    const int f0 = blockIdx.x * 32, s0 = blockIdx.y * 32;
    const float mu = musig[b], rs = musig[16 + b];
    const int tid = threadIdx.x;
    {
        const int s_loc = tid >> 3, c4 = (tid & 7) * 4;
        const size_t idx = (size_t)(s0 + s_loc) * FF + f0 + c4;
        const float4 xv = *(const float4*)&x[((size_t)b << 20) + idx];
        const float4 wv = *(const float4*)&lw[idx];
        const float4 bv = *(const float4*)&lb[idx];
        bf16x4 o;
        o[0] = (bf16_t)((xv.x - mu) * rs * wv.x + bv.x);
        o[1] = (bf16_t)((xv.y - mu) * rs * wv.y + bv.y);
        o[2] = (bf16_t)((xv.z - mu) * rs * wv.z + bv.z);
        o[3] = (bf16_t)((xv.w - mu) * rs * wv.w + bv.w);
        t[s_loc][c4 + 0] = o[0];
        t[s_loc][c4 + 1] = o[1];
        t[s_loc][c4 + 2] = o[2];
        t[s_loc][c4 + 3] = o[3];
        if (Xn) *(bf16x4*)&Xn[((size_t)b << 20) + idx] = o;
    }
    __syncthreads();
    {
        const int f_loc = tid >> 3, s4 = (tid & 7) * 4;
        bf16x4 o;
        o[0] = t[s4 + 0][f_loc];
        o[1] = t[s4 + 1][f_loc];
        o[2] = t[s4 + 2][f_loc];
        o[3] = t[s4 + 3][f_loc];
        *(bf16x4*)&Y[((size_t)b << 20) + (size_t)(f0 + f_loc) * SS + s0 + s4] = o;
    }
}

// ---------------------------------------------------------------- Wv -> bf16
__global__ __launch_bounds__(256) void cast_wv(const float* __restrict__ Wv,
                                               bf16_t* __restrict__ Wvb) {
    const size_t i = ((size_t)blockIdx.x * 256 + threadIdx.x) * 4;
    const float4 v = *(const float4*)&Wv[i];
    bf16x4 o;
    o[0] = (bf16_t)v.x; o[1] = (bf16_t)v.y; o[2] = (bf16_t)v.z; o[3] = (bf16_t)v.w;
    *(bf16x4*)&Wvb[i] = o;
}

// ------------------------------- Q,K: 4 rows/wave, weight loads amortized x4
__global__ __launch_bounds__(256) void qk_kernel(const bf16_t* __restrict__ Y,
                                                 const float* __restrict__ Wq,
                                                 const float* __restrict__ bq,
                                                 const float* __restrict__ Wk,
                                                 const float* __restrict__ bk,
                                                 float* __restrict__ Qo,
                                                 float* __restrict__ Ko) {
    const int w = threadIdx.x >> 6, lane = threadIdx.x & 63;
    const int row0 = blockIdx.x * 16 + w * 4;        // b*512 + f, 4 rows per wave
    const bf16_t* y0 = Y + (size_t)row0 * SS;
    float qa[4][4] = {}, ka[4][4] = {};              // [row][r]
#pragma unroll
    for (int c = 0; c < 4; ++c) {
        const int s = c * 512 + lane * 8;
        float yf[4][8];
#pragma unroll
        for (int rr = 0; rr < 4; ++rr) {
            const bf16x8 yv = *(const bf16x8*)&y0[(size_t)rr * SS + s];
#pragma unroll
            for (int j = 0; j < 8; ++j) yf[rr][j] = (float)yv[j];
        }
#pragma unroll
        for (int r = 0; r < 4; ++r) {
            const float4 a0 = *(const float4*)&Wq[r * SS + s];
            const float4 a1 = *(const float4*)&Wq[r * SS + s + 4];
            const float4 c0 = *(const float4*)&Wk[r * SS + s];
            const float4 c1 = *(const float4*)&Wk[r * SS + s + 4];
#pragma unroll
            for (int rr = 0; rr < 4; ++rr) {
                qa[rr][r] += yf[rr][0]*a0.x + yf[rr][1]*a0.y + yf[rr][2]*a0.z + yf[rr][3]*a0.w
                           + yf[rr][4]*a1.x + yf[rr][5]*a1.y + yf[rr][6]*a1.z + yf[rr][7]*a1.w;
                ka[rr][r] += yf[rr][0]*c0.x + yf[rr][1]*c0.y + yf[rr][2]*c0.z + yf[rr][3]*c0.w
                           + yf[rr][4]*c1.x + yf[rr][5]*c1.y + yf[rr][6]*c1.z + yf[rr][7]*c1.w;
            }
        }
    }
#pragma unroll
    for (int off = 32; off > 0; off >>= 1) {
#pragma unroll
        for (int rr = 0; rr < 4; ++rr)
#pragma unroll
            for (int r = 0; r < 4; ++r) {
                qa[rr][r] += __shfl_down(qa[rr][r], off);
                ka[rr][r] += __shfl_down(ka[rr][r], off);
            }
    }
    if (lane == 0) {
#pragma unroll
        for (int rr = 0; rr < 4; ++rr)
#pragma unroll
            for (int r = 0; r < 4; ++r) {
                Qo[(size_t)(row0 + rr) * 4 + r] = qa[rr][r] + bq[r];
                Ko[(size_t)(row0 + rr) * 4 + r] = ka[rr][r] + bk[r];
            }
    }
}

// ----------------------------------- A = softmax(Q K^T / sqrt(4)), bf16 output
__global__ __launch_bounds__(256) void softmax_kernel(const float* __restrict__ Qo,
                                                      const float* __restrict__ Ko,
                                                      bf16_t* __restrict__ Aout) {
    const int w = threadIdx.x >> 6, lane = threadIdx.x & 63;
    const int row = blockIdx.x * 4 + w;              // b*512 + f
    const int b = row >> 9;
    const float4 q = *(const float4*)&Qo[(size_t)row * 4];
    const float* kb = Ko + (size_t)b * FF * 4;
    float sc[8];
#pragma unroll
    for (int j = 0; j < 8; ++j) {
        const float4 kv = *(const float4*)&kb[(lane * 8 + j) * 4];
        sc[j] = (q.x*kv.x + q.y*kv.y + q.z*kv.z + q.w*kv.w) * 0.5f;
    }
    float mx = sc[0];
#pragma unroll
    for (int j = 1; j < 8; ++j) mx = fmaxf(mx, sc[j]);
#pragma unroll
    for (int off = 32; off > 0; off >>= 1) mx = fmaxf(mx, __shfl_xor(mx, off));
    float sum = 0.f;
#pragma unroll
    for (int j = 0; j < 8; ++j) { sc[j] = __expf(sc[j] - mx); sum += sc[j]; }
#pragma unroll
    for (int off = 32; off > 0; off >>= 1) sum += __shfl_xor(sum, off);
    const float inv = 1.0f / sum;
    bf16x8 o;
#pragma unroll
    for (int j = 0; j < 8; ++j) o[j] = (bf16_t)(sc[j] * inv);
    *(bf16x8*)&Aout[(size_t)row * FF + lane * 8] = o;
}

// --------------------------------------------------------------- NT bf16 GEMM
// r9/r10-proven read-ahead pipeline (66 us, MfmaUtil 43%): staggered stages
// (one STA/STB pair per phase), counted vmcnt(2) at P2/P4 entry, counted
// lgkm(4/8/4/8), ping-pong register banks, 2 barriers/tile. (r11's all-8-
// stages-at-P1 variant REGRESSED to 72.5 us — reverted.)
// EPI: 0 = plain bf16 C-write; 1 = fused (x/lw/lb fp32); 2 = fused (Xn bf16).
template<int EPI>
__device__ __forceinline__ void gemm_impl(
        const bf16_t* __restrict__ Abase, long long strideA, int lda,
        const bf16_t* __restrict__ Bbase, long long strideB, int ldb,
        bf16_t* __restrict__ Cbase, long long strideC, int ldc,
        int NTILES, const float* __restrict__ bias_m,
        const float* __restrict__ xp, const float* __restrict__ lwp,
        const float* __restrict__ lbp, const bf16_t* __restrict__ xnp,
        const float* __restrict__ musig,
        const float* __restrict__ alphap, const float* __restrict__ betap,
        float* __restrict__ outp) {
    __shared__ __align__(16) bf16_t As[2][16384];   // [buf][kk*8192 + row*32 + swz]
    __shared__ __align__(16) bf16_t Bs[2][16384];   // total 128 KiB
    const int tid = threadIdx.x;
    const int w = tid >> 6, lane = tid & 63;

    // XCD-bijective swizzle (nwg = 256, 256 % 8 == 0)
    const int nchunk = gridDim.x >> 3;                               // 32
    const int wgid = (blockIdx.x & 7) * nchunk + (blockIdx.x >> 3);
    const int bz = wgid >> 4;            // batch
    const int rem = wgid & 15;
    const int m0 = (rem & 7) * 256, n0 = (rem >> 3) * 256;

    const bf16_t* A = Abase + (size_t)bz * (size_t)strideA;
    const bf16_t* B = Bbase + (size_t)bz * (size_t)strideB;
    bf16_t* C = Cbase + (size_t)bz * (size_t)strideC;
    const int wm = w >> 2, wn = w & 3;   // wave tile rows wm*128.., cols wn*64..

    const int rr0 = (w * 2 + 0) * 16 + (lane >> 2);
    const int rr1 = (w * 2 + 1) * 16 + (lane >> 2);
    const int sw0 = ((lane & 3) ^ ((rr0 >> 1) & 3)) * 8;
    const int sw1 = ((lane & 3) ^ ((rr1 >> 1) & 3)) * 8;
    const bf16_t* gA0 = A + (size_t)(m0 + rr0) * lda + sw0;
    const bf16_t* gA1 = A + (size_t)(m0 + rr1) * lda + sw1;
    const bf16_t* gB0 = B + (size_t)(n0 + rr0) * ldb + sw0;
    const bf16_t* gB1 = B + (size_t)(n0 + rr1) * ldb + sw1;
    const int d0 = (w * 2 + 0) * 512;
    const int d1 = (w * 2 + 1) * 512;

#define STA(bi, h, ko) do {                                                          \
    __builtin_amdgcn_global_load_lds(                                                \
        (const __attribute__((address_space(1))) unsigned int*)(gA0 + (ko) + (h)*32),\
        (__attribute__((address_space(3))) unsigned int*)&As[bi][(h)*8192 + d0], 16, 0, 0); \
    __builtin_amdgcn_global_load_lds(                                                \
        (const __attribute__((address_space(1))) unsigned int*)(gA1 + (ko) + (h)*32),\
        (__attribute__((address_space(3))) unsigned int*)&As[bi][(h)*8192 + d1], 16, 0, 0); \
} while (0)
#define STB(bi, h, ko) do {                                                          \
    __builtin_amdgcn_global_load_lds(                                                \
        (const __attribute__((address_space(1))) unsigned int*)(gB0 + (ko) + (h)*32),\
        (__attribute__((address_space(3))) unsigned int*)&Bs[bi][(h)*8192 + d0], 16, 0, 0); \
    __builtin_amdgcn_global_load_lds(                                                \
        (const __attribute__((address_space(1))) unsigned int*)(gB1 + (ko) + (h)*32),\
        (__attribute__((address_space(3))) unsigned int*)&Bs[bi][(h)*8192 + d1], 16, 0, 0); \
} while (0)

    const int cs = lane >> 4;
    int offA[2][8], offB[2][4];
#pragma unroll
    for (int kk = 0; kk < 2; ++kk) {
#pragma unroll
        for (int mt = 0; mt < 8; ++mt) {
            const int r = wm * 128 + mt * 16 + (lane & 15);
            offA[kk][mt] = kk * 8192 + r * 32 + ((cs ^ ((r >> 1) & 3)) << 3);
        }
#pragma unroll
        for (int nt = 0; nt < 4; ++nt) {
            const int r = wn * 64 + nt * 16 + (lane & 15);
            offB[kk][nt] = kk * 8192 + r * 32 + ((cs ^ ((r >> 1) & 3)) << 3);
        }
    }

#define RD_A(dst, base, kk, mh) do { _Pragma("unroll")                        \
    for (int i = 0; i < 4; ++i) dst[i] = *(const bf16x8*)&(base)[offA[kk][(mh)*4 + i]]; } while (0)
#define RD_B(dst, base, kk) do { _Pragma("unroll")                            \
    for (int i = 0; i < 4; ++i) dst[i] = *(const bf16x8*)&(base)[offB[kk][i]]; } while (0)
#define MFMA16X(af, bfr, mh) do { _Pragma("unroll")                           \
    for (int i = 0; i < 4; ++i) { _Pragma("unroll")                           \
        for (int nt = 0; nt < 4; ++nt)                                        \
            acc[(mh)*4 + i][nt] = __builtin_amdgcn_mfma_f32_16x16x32_bf16(    \
                af[i], bfr[nt], acc[(mh)*4 + i][nt], 0, 0, 0); } } while (0)
#define VMC(n) asm volatile("s_waitcnt vmcnt(" #n ")" ::: "memory")
#define HBAR  __builtin_amdgcn_s_barrier()
#define LGKM(n) do { asm volatile("s_waitcnt lgkmcnt(" #n ")" ::: "memory");  \
                     __builtin_amdgcn_sched_barrier(0); } while (0)
#define SBAR  __builtin_amdgcn_sched_barrier(0)
#define PRIO1 __builtin_amdgcn_s_setprio(1)
#define PRIO0 __builtin_amdgcn_s_setprio(0)

    f32x4 acc[8][4] = {};
    bf16x8 afA[4], afB[4], bfrA[4], bfrB[4];
    const int mask = NTILES - 1;

    // prologue: tile 0 into buf 0; force h0 landed; read C1
    STA(0, 0, 0); STB(0, 0, 0); STA(0, 1, 0); STB(0, 1, 0);
    VMC(4); HBAR;
    RD_A(afA, As[0], 0, 0); RD_B(bfrA, Bs[0], 0);

    for (int t = 0; t < NTILES; ++t) {
        const int cur = t & 1, oth = cur ^ 1;
        const int ko = ((t + 1) & mask) * 64;
        const bf16_t* as  = As[cur];
        const bf16_t* bs  = Bs[cur];
        const bf16_t* asn = As[oth];
        const bf16_t* bsn = Bs[oth];
        // P1: read C2; stage A-h0 of t+1; consume C1
        RD_A(afB, as, 0, 1); SBAR;
        STA(oth, 0, ko); SBAR;
        LGKM(4);
        PRIO1; MFMA16X(afA, bfrA, 0); PRIO0; SBAR;
        // P2: h1-of-cur landed; read C3; stage B-h0 of t+1; consume C2
        VMC(2); HBAR;
        RD_A(afA, as, 1, 0); RD_B(bfrB, bs, 1); SBAR;
        STB(oth, 0, ko); SBAR;
        LGKM(8);
        PRIO1; MFMA16X(afB, bfrA, 1); PRIO0; SBAR;
        // P3: read C4; stage A-h1 of t+1; consume C3
        RD_A(afB, as, 1, 1); SBAR;
        STA(oth, 1, ko); SBAR;
        LGKM(4);
        PRIO1; MFMA16X(afA, bfrB, 0); PRIO0; SBAR;
        // P4: h0-of-next landed; read next C1; stage B-h1 of t+1; consume C4
        VMC(2); HBAR;
        RD_A(afA, asn, 0, 0); RD_B(bfrA, bsn, 0); SBAR;
        STB(oth, 1, ko); SBAR;
        LGKM(8);
        PRIO1; MFMA16X(afB, bfrB, 1); PRIO0; SBAR;
    }
#undef STA
#undef STB
#undef RD_A
#undef RD_B
#undef MFMA16X
#undef VMC
#undef HBAR
#undef LGKM
#undef SBAR
#undef PRIO1
#undef PRIO0

    if constexpr (EPI == 0) {
        // Plain epilogue: C/D layout row=(lane>>4)*4+reg, col=lane&15
#pragma unroll
        for (int mt = 0; mt < 8; ++mt) {
#pragma unroll
            for (int r = 0; r < 4; ++r) {
                const int row = m0 + wm * 128 + mt * 16 + ((lane >> 4) << 2) + r;
                const float bm = bias_m ? bias_m[row] : 0.0f;
#pragma unroll
                for (int nt = 0; nt < 4; ++nt) {
                    const int col = n0 + wn * 64 + nt * 16 + (lane & 15);
                    C[(size_t)row * ldc + col] = (bf16_t)(acc[mt][nt][r] + bm);
                }
            }
        }
    } else {
        // Fused epilogue, coalesced via double-banked LDS + one barrier/chunk.
        asm volatile("s_waitcnt vmcnt(0) lgkmcnt(0)" ::: "memory");
        __syncthreads();
        float* lsc0 = (float*)&As[0][0];     // 32 KiB = [32][256] f32
        float* lsc1 = (float*)&As[1][0];     // second bank
        const float alpha = alphap[0];
        const float onepb = 1.0f + betap[0];
        float mu = 0.f, rs = 0.f;
        if constexpr (EPI == 1) { mu = musig[bz]; rs = musig[16 + bz]; }
        const float* xb = (EPI == 1) ? xp + ((size_t)bz << 20) : nullptr;
        const bf16_t* xnb = (EPI == 2) ? xnp + ((size_t)bz << 20) : nullptr;
        float* ob = outp + ((size_t)bz << 20);
        const int lrow = wm * 16 + ((lane >> 4) << 2);
        const int lcol = wn * 64 + (lane & 15);
        const int gr = tid >> 4;             // 0..31 local row
        const int gc = (tid & 15) * 16;      // col base, 16 consecutive floats
#define SCAT(mt, bank) do { _Pragma("unroll")                                 \
    for (int r = 0; r < 4; ++r) { _Pragma("unroll")                           \
        for (int nt = 0; nt < 4; ++nt)                                        \
            (bank)[(lrow + r) * 256 + lcol + nt * 16] = acc[mt][nt][r]; } } while (0)
        SCAT(0, lsc0);
        __syncthreads();
#pragma unroll
        for (int mt = 0; mt < 8; ++mt) {
            float* bank  = (mt & 1) ? lsc1 : lsc0;
            float* nbank = (mt & 1) ? lsc0 : lsc1;
            const int grow = m0 + (gr >> 4) * 128 + mt * 16 + (gr & 15);
            const size_t idx = (size_t)grow * FF + n0 + gc;
            // hoisted global loads (independent of LDS)
            const bf16x8 vt0 = *(const bf16x8*)&A[(size_t)grow * lda + n0 + gc];
            const bf16x8 vt1 = *(const bf16x8*)&A[(size_t)grow * lda + n0 + gc + 8];
            bf16x8 xn0, xn1;
            float4 xv[4], wv[4], bv4[4];
            if constexpr (EPI == 2) {
                xn0 = *(const bf16x8*)&xnb[idx];
                xn1 = *(const bf16x8*)&xnb[idx + 8];
            } else {
#pragma unroll
                for (int j = 0; j < 4; ++j) {
                    xv[j]  = *(const float4*)&xb[idx + j * 4];
                    wv[j]  = *(const float4*)&lwp[idx + j * 4];
                    bv4[j] = *(const float4*)&lbp[idx + j * 4];
                }
            }
            if (mt < 7) {
                switch (mt + 1) {   // static index per rule #20 (unrolled loop)
                    case 1: SCAT(1, nbank); break;
                    case 2: SCAT(2, nbank); break;
                    case 3: SCAT(3, nbank); break;
                    case 4: SCAT(4, nbank); break;
                    case 5: SCAT(5, nbank); break;
                    case 6: SCAT(6, nbank); break;
                    case 7: SCAT(7, nbank); break;
                }
            }
#pragma unroll
            for (int j = 0; j < 4; ++j) {
                const float4 av = *(const float4*)&bank[gr * 256 + gc + j * 4];
                float4 o;
                if constexpr (EPI == 2) {
                    const int e = (j & 1) * 4;
                    const bf16x8& xs = (j < 2) ? xn0 : xn1;
                    const bf16x8& vs = (j < 2) ? vt0 : vt1;
                    o.x = (float)xs[e + 0] + alpha * av.x + onepb * (float)vs[e + 0];
                    o.y = (float)xs[e + 1] + alpha * av.y + onepb * (float)vs[e + 1];
                    o.z = (float)xs[e + 2] + alpha * av.z + onepb * (float)vs[e + 2];
                    o.w = (float)xs[e + 3] + alpha * av.w + onepb * (float)vs[e + 3];
                } else {
                    const int e = (j & 1) * 4;
                    const bf16x8& vs = (j < 2) ? vt0 : vt1;
                    o.x = (xv[j].x - mu) * rs * wv[j].x + bv4[j].x + alpha * av.x + onepb * (float)vs[e + 0];
                    o.y = (xv[j].y - mu) * rs * wv[j].y + bv4[j].y + alpha * av.y + onepb * (float)vs[e + 1];
                    o.z = (xv[j].z - mu) * rs * wv[j].z + bv4[j].z + alpha * av.z + onepb * (float)vs[e + 2];
                    o.w = (xv[j].w - mu) * rs * wv[j].w + bv4[j].w + alpha * av.w + onepb * (float)vs[e + 3];
                }
                *(float4*)&ob[idx + j * 4] = o;
            }
            __syncthreads();
        }
#undef SCAT
    }
}

__global__ __launch_bounds__(512, 2) void g1_mm(
        const bf16_t* A, long long sA, int lda, const bf16_t* B, long long sB, int ldb,
        bf16_t* C, long long sC, int ldc, int NT, const float* bias_m) {
    gemm_impl<0>(A, sA, lda, B, sB, ldb, C, sC, ldc, NT, bias_m,
                 nullptr, nullptr, nullptr, nullptr, nullptr, nullptr, nullptr, nullptr);
}

__global__ __launch_bounds__(512, 2) void g2_mm_full(
        const bf16_t* A, long long sA, int lda, const bf16_t* B, long long sB, int ldb,
        int NT, const float* xp, const float* lwp, const float* lbp,
        const float* musig, const float* alphap, const float* betap, float* outp) {
    gemm_impl<1>(A, sA, lda, B, sB, ldb, nullptr, 0, FF, NT, nullptr,
                 xp, lwp, lbp, nullptr, musig, alphap, betap, outp);
}

__global__ __launch_bounds__(512, 2) void g2_mm_lite(
        const bf16_t* A, long long sA, int lda, const bf16_t* B, long long sB, int ldb,
        int NT, const bf16_t* xnp,
        const float* musig, const float* alphap, const float* betap, float* outp) {
    gemm_impl<2>(A, sA, lda, B, sB, ldb, nullptr, 0, FF, NT, nullptr,
                 nullptr, nullptr, nullptr, xnp, musig, alphap, betap, outp);
}

extern "C" void kernel_launch(void* const* d_in, const int* in_sizes, int n_in,
                              void* d_out, int out_size, void* d_ws, size_t ws_size,
                              hipStream_t stream) {
    const float* x   = (const float*)d_in[0];
    const float* Wq  = (const float*)d_in[1];
    const float* bq  = (const float*)d_in[2];
    const float* Wk  = (const float*)d_in[3];
    const float* bk  = (const float*)d_in[4];
    const float* Wv  = (const float*)d_in[5];
    const float* bv  = (const float*)d_in[6];
    const float* lw  = (const float*)d_in[7];
    const float* lb  = (const float*)d_in[8];
    const float* alp = (const float*)d_in[9];
    const float* bet = (const float*)d_in[10];
    float* out = (float*)d_out;

    char* ws = (char*)d_ws;
    float*  musig = (float*)(ws + 128);         // 32 f32: mu[16], rsig[16]
    float*  Qo    = (float*)(ws + 256);         // 16*512*4 f32 = 128 KiB
    float*  Ko    = (float*)(ws + 256 + 131072);
    bf16_t* Wvb   = (bf16_t*)(ws + 262400);     // 2048*2048 bf16 = 8 MiB
    bf16_t* Asm   = (bf16_t*)(ws + 8651008);    // 16*512*512 bf16 = 8 MiB
    float*  partials = (float*)(ws + 8651008);  // 2048 f32 — dead before Asm written
    bf16_t* Vt    = (bf16_t*)(ws + 17039616);   // 16*2048*512 bf16 = 32 MiB
    bf16_t* Y     = (bf16_t*)(ws + 50594048);   // 16*512*2048 bf16 = 32 MiB
    bf16_t* Xn    = (bf16_t*)(ws + 84148480);   // 16*2048*512 bf16 = 32 MiB (optional)
    const bool lite = ws_size >= (size_t)117702912;

    stats_kernel<<<dim3(64, 16), 256, 0, stream>>>(x, partials);
    finalize_stats<<<1, 256, 0, stream>>>(partials, musig);
    cast_wv<<<4096, 256, 0, stream>>>(Wv, Wvb);
    ynorm_kernel<<<dim3(16, 64, 16), 256, 0, stream>>>(x, lw, lb, musig, Y,
                                                       lite ? Xn : (bf16_t*)nullptr);
    qk_kernel<<<512, 256, 0, stream>>>(Y, Wq, bq, Wk, bk, Qo, Ko);
    softmax_kernel<<<2048, 256, 0, stream>>>(Qo, Ko, Asm);
    // Vt[b,t,f] = sum_s Wv[t,s]*Y[b,f,s] + bv[t]   (M=2048,N=512,K=2048 -> 32 tiles)
    g1_mm<<<256, 512, 0, stream>>>(Wvb, 0, SS, Y, 1 << 20, SS, Vt, 1 << 20, FF, 32, bv);
    // out[b,t,f] = x_norm + alpha*(Vt.Asm^T) + (1+beta)*Vt  (M=2048,N=512,K=512)
    if (lite) {
        g2_mm_lite<<<256, 512, 0, stream>>>(Vt, 1 << 20, FF, Asm, FF * FF, FF, 8,
                                            Xn, musig, alp, bet, out);
    } else {
        g2_mm_full<<<256, 512, 0, stream>>>(Vt, 1 << 20, FF, Asm, FF * FF, FF, 8,
                                            x, lw, lb, musig, alp, bet, out);
    }
}